// Round 1
// baseline (341.419 us; speedup 1.0000x reference)
//
#include <hip/hip_runtime.h>
#include <stdint.h>
#include <math.h>

#define TK 16384
#define DD 2048
#define RR 256
#define EE 8
#define HH 512
#define NSEG_MAX 264
#define NPAIR_MAX (NSEG_MAX * 128)

typedef __attribute__((ext_vector_type(4))) float f32x4;
typedef __attribute__((ext_vector_type(8))) short s16x8;
typedef __attribute__((ext_vector_type(8))) unsigned short u16x8;
typedef __attribute__((ext_vector_type(4))) unsigned short u16x4;
typedef unsigned short ushort_t;

__device__ inline unsigned short f2bf(float f) {
  union { float f; unsigned u; } v; v.f = f;
  unsigned r = v.u + 0x7fffu + ((v.u >> 16) & 1u);
  return (unsigned short)(r >> 16);
}

__device__ inline void gll16(const void* g, void* l) {
  __builtin_amdgcn_global_load_lds(
      (const __attribute__((address_space(1))) void*)g,
      (__attribute__((address_space(3))) void*)l, 16, 0, 0);
}

__device__ inline u16x8 pack8(f32x4 a, f32x4 b) {
  u16x8 r;
  r[0] = f2bf(a.x); r[1] = f2bf(a.y); r[2] = f2bf(a.z); r[3] = f2bf(a.w);
  r[4] = f2bf(b.x); r[5] = f2bf(b.y); r[6] = f2bf(b.z); r[7] = f2bf(b.w);
  return r;
}

// ---------------- prep: convert + transpose weights to bf16 [N][K] layouts ----
__global__ void k_prep(const float* V, const float* U, const float* W1, const float* W2,
                       ushort_t* Vt, ushort_t* Ut, ushort_t* W1t, ushort_t* W2t) {
  int i = blockIdx.x * 256 + threadIdx.x;
  if (i < 524288) {                       // Vt[r][d] = V[d][r]
    int r = i >> 11, d = i & 2047;
    Vt[i] = f2bf(V[d * RR + r]);
  } else if (i < 1048576) {               // Ut[d][r] = U[r][d]
    int j = i - 524288;
    int d = j >> 8, r = j & 255;
    Ut[j] = f2bf(U[r * DD + d]);
  } else if (i < 2097152) {               // W1t[e][h][r] = W1[e][r][h]
    int j = i - 1048576;
    int e = j >> 17, rem = j & 131071;
    int hh = rem >> 8, r = rem & 255;
    W1t[j] = f2bf(W1[e * 131072 + r * HH + hh]);
  } else if (i < 3145728) {               // W2t[e][r][h] = W2[e][h][r]
    int j = i - 2097152;
    int e = j >> 17, rem = j & 131071;
    int r = rem >> 9, hh = rem & 511;
    W2t[j] = f2bf(W2[e * 131072 + hh * RR + r]);
  }
}

// ---------------- Veff[d][e] = sum_r V[d][r]*Wr[r][e]  (fp32, for exact routing)
__global__ void k_veff(const float* V, const float* Wr, float* Veff) {
  int i = blockIdx.x * 256 + threadIdx.x;   // 16384
  int d = i >> 3, e = i & 7;
  float acc = 0.f;
  for (int r = 0; r < RR; ++r) acc += V[d * RR + r] * Wr[r * EE + e];
  Veff[i] = acc;
}

// ---------------- Uh[r] = sum_d U[r][d]*Wh[d] ------------------------------
__global__ void k_uh(const float* U, const float* Wh, float* Uh) {
  int wave = threadIdx.x >> 6, lane = threadIdx.x & 63;
  int r = blockIdx.x * 4 + wave;
  const f32x4* u4 = (const f32x4*)(U + (size_t)r * DD);
  const f32x4* w4 = (const f32x4*)Wh;
  float acc = 0.f;
  #pragma unroll
  for (int it = 0; it < 8; ++it) {
    f32x4 a = u4[it * 64 + lane], b = w4[it * 64 + lane];
    acc += a.x * b.x + a.y * b.y + a.z * b.z + a.w * b.w;
  }
  #pragma unroll
  for (int o = 32; o; o >>= 1) acc += __shfl_down(acc, o, 64);
  if (lane == 0) Uh[r] = acc;
}

// ---------------- router: fp32 logits = h@Veff + br; top-2; counts ----------
__global__ __launch_bounds__(256) void k_router(const float* h, const float* Veff,
                                                const float* br, int* topi, float* topw,
                                                int* counts) {
  __shared__ float lv[DD * EE];   // 64 KB
  __shared__ float ex[32][8];
  __shared__ int lcnt[8];
  int t = threadIdx.x;
  f32x4* lv4 = (f32x4*)lv;
  const f32x4* gv4 = (const f32x4*)Veff;
  #pragma unroll
  for (int it = 0; it < 16; ++it) lv4[it * 256 + t] = gv4[it * 256 + t];
  if (t < 8) lcnt[t] = 0;
  __syncthreads();

  int tok_l = t >> 3, sub = t & 7, ep = sub >> 2, kq = sub & 3;
  int tok = blockIdx.x * 32 + tok_l;
  const f32x4* h4 = (const f32x4*)(h + (size_t)tok * DD);
  float a0 = 0.f, a1 = 0.f, a2 = 0.f, a3 = 0.f;
  for (int it = 0; it < 128; ++it) {
    int i4 = it * 4 + kq;
    f32x4 hv = h4[i4];
    int d0 = i4 * 4;
    #pragma unroll
    for (int j = 0; j < 4; ++j) {
      f32x4 vf = lv4[(d0 + j) * 2 + ep];
      float hd = hv[j];
      a0 += hd * vf.x; a1 += hd * vf.y; a2 += hd * vf.z; a3 += hd * vf.w;
    }
  }
  a0 += __shfl_xor(a0, 1, 64); a0 += __shfl_xor(a0, 2, 64);
  a1 += __shfl_xor(a1, 1, 64); a1 += __shfl_xor(a1, 2, 64);
  a2 += __shfl_xor(a2, 1, 64); a2 += __shfl_xor(a2, 2, 64);
  a3 += __shfl_xor(a3, 1, 64); a3 += __shfl_xor(a3, 2, 64);
  if (kq == 0) {
    ex[tok_l][ep * 4 + 0] = a0 + br[ep * 4 + 0];
    ex[tok_l][ep * 4 + 1] = a1 + br[ep * 4 + 1];
    ex[tok_l][ep * 4 + 2] = a2 + br[ep * 4 + 2];
    ex[tok_l][ep * 4 + 3] = a3 + br[ep * 4 + 3];
  }
  __syncthreads();
  if (t < 32) {
    int token = blockIdx.x * 32 + t;
    float l[8];
    #pragma unroll
    for (int e = 0; e < 8; ++e) l[e] = ex[t][e];
    float best = -1e30f; int bi = 0;
    #pragma unroll
    for (int e = 0; e < 8; ++e) if (l[e] > best) { best = l[e]; bi = e; }
    float sec = -1e30f; int si = 0;
    #pragma unroll
    for (int e = 0; e < 8; ++e) if (e != bi && l[e] > sec) { sec = l[e]; si = e; }
    float w0 = 1.f / (1.f + expf(sec - best));
    topi[token * 2 + 0] = bi; topi[token * 2 + 1] = si;
    topw[token * 2 + 0] = w0; topw[token * 2 + 1] = 1.f - w0;
    atomicAdd(&lcnt[bi], 1);
    atomicAdd(&lcnt[si], 1);
  }
  __syncthreads();
  if (t < 8) atomicAdd(&counts[t], lcnt[t]);
}

// ---------------- bases: padded per-expert segments -------------------------
// ctrl layout (ints): [0..7]=counts [8..15]=gcursor [16..16+264)=seg2expert
__global__ void k_bases(int* ctrl) {
  if (threadIdx.x == 0) {
    int cum = 0;
    for (int e = 0; e < 8; ++e) {
      int c = ctrl[e];
      int segs = (c + 127) >> 7;
      ctrl[8 + e] = cum;
      for (int s2 = 0; s2 < segs; ++s2) ctrl[16 + (cum >> 7) + s2] = e;
      cum += segs << 7;
    }
    for (int s2 = cum >> 7; s2 < NSEG_MAX; ++s2) ctrl[16 + s2] = -1;
  }
}

// ---------------- scatter tokens into per-expert pair lists -----------------
__global__ __launch_bounds__(256) void k_scatter(const int* topi, const float* topw,
                                                 int* ctrl, int* pair_t, float* pair_w) {
  __shared__ int lcnt[8], lbase[8];
  int t = threadIdx.x;
  if (t < 8) lcnt[t] = 0;
  __syncthreads();
  int slot = blockIdx.x * 256 + t;
  int e = topi[slot];
  float wv = topw[slot];
  int lp = atomicAdd(&lcnt[e], 1);
  __syncthreads();
  if (t < 8) lbase[t] = atomicAdd(&ctrl[8 + t], lcnt[t]);
  __syncthreads();
  int p = lbase[e] + lp;
  pair_t[p] = slot >> 1;
  pair_w[p] = wv;
}

#define GEMM_COMPUTE(AS, BS)                                                          \
  _Pragma("unroll")                                                                   \
  for (int ks = 0; ks < 2; ++ks) {                                                    \
    s16x8 af[4], bq[4];                                                               \
    _Pragma("unroll")                                                                 \
    for (int i = 0; i < 4; ++i)                                                       \
      af[i] = *(const s16x8*)&AS[(wr * 64 + i * 16 + ln) * 64 + ks * 32 + hi * 8];    \
    _Pragma("unroll")                                                                 \
    for (int j = 0; j < 4; ++j)                                                       \
      bq[j] = *(const s16x8*)&BS[(wc * 64 + j * 16 + ln) * 64 + ks * 32 + hi * 8];    \
    _Pragma("unroll")                                                                 \
    for (int i = 0; i < 4; ++i)                                                       \
      _Pragma("unroll")                                                               \
      for (int j = 0; j < 4; ++j)                                                     \
        acc[i][j] = __builtin_amdgcn_mfma_f32_16x16x32_bf16(af[i], bq[j], acc[i][j], 0, 0, 0); \
  }

// ---------------- gemm_z: z[T][R] = h @ V  (A fp32->bf16 reg-staged) --------
// also zfin = 0.75*z (fp32)
__global__ __launch_bounds__(256, 2) void k_gemm_z(const float* h, const ushort_t* Vt,
                                                   ushort_t* zb, float* zfin) {
  __shared__ ushort_t As[2][8192];
  __shared__ ushort_t Bs[2][8192];
  int hw = blockIdx.x;
  int bid = (hw & 7) * 32 + (hw >> 3);      // XCD swizzle (256 = 8*32)
  int mt = bid >> 1, nt = bid & 1;
  int m0 = mt * 128, n0 = nt * 128;
  int t = threadIdx.x;
  int lane = t & 63, wave = t >> 6;
  int wr = wave >> 1, wc = wave & 1;
  int ln = lane & 15, hi = lane >> 4;

  int arow = t >> 1, ahalf = t & 1;
  const float* aptr = h + (size_t)(m0 + arow) * DD + ahalf * 32;

  f32x4 acc[4][4];
  #pragma unroll
  for (int i = 0; i < 4; ++i)
    #pragma unroll
    for (int j = 0; j < 4; ++j) acc[i][j] = (f32x4){0.f, 0.f, 0.f, 0.f};

  f32x4 pf[8];
  {  // prologue k0 = 0
    const f32x4* ap = (const f32x4*)aptr;
    #pragma unroll
    for (int q = 0; q < 8; ++q) pf[q] = ap[q];
    #pragma unroll
    for (int u = 0; u < 4; ++u) {
      int idx = u * 256 + t;
      gll16(Vt + (size_t)(n0 + (idx >> 3)) * DD + (idx & 7) * 8, &Bs[0][idx * 8]);
    }
    u16x8* dst = (u16x8*)&As[0][arow * 64 + ahalf * 32];
    #pragma unroll
    for (int q = 0; q < 4; ++q) dst[q] = pack8(pf[2 * q], pf[2 * q + 1]);
  }
  __syncthreads();

  for (int s = 0; s < 32; ++s) {
    int cb = s & 1, xb = cb ^ 1;
    if (s < 31) {
      int k1 = (s + 1) * 64;
      const f32x4* ap = (const f32x4*)(aptr + k1);
      #pragma unroll
      for (int q = 0; q < 8; ++q) pf[q] = ap[q];
      #pragma unroll
      for (int u = 0; u < 4; ++u) {
        int idx = u * 256 + t;
        gll16(Vt + (size_t)(n0 + (idx >> 3)) * DD + k1 + (idx & 7) * 8, &Bs[xb][idx * 8]);
      }
    }
    GEMM_COMPUTE(As[cb], Bs[cb]);
    if (s < 31) {
      u16x8* dst = (u16x8*)&As[xb][arow * 64 + ahalf * 32];
      #pragma unroll
      for (int q = 0; q < 4; ++q) dst[q] = pack8(pf[2 * q], pf[2 * q + 1]);
    }
    __syncthreads();
  }

  #pragma unroll
  for (int i = 0; i < 4; ++i)
    #pragma unroll
    for (int j = 0; j < 4; ++j)
      #pragma unroll
      for (int r = 0; r < 4; ++r) {
        int row = m0 + wr * 64 + i * 16 + hi * 4 + r;
        int col = n0 + wc * 64 + j * 16 + ln;
        float v = acc[i][j][r];
        zb[(size_t)row * RR + col] = f2bf(v);
        zfin[(size_t)row * RR + col] = 0.75f * v;
      }
}

// ---------------- e1: hidden = gelu(gather(zb) @ W1[e] + b1) ---------------
__global__ __launch_bounds__(256, 2) void k_e1(const ushort_t* zb, const ushort_t* W1t,
                                               const float* b1, const int* ctrl,
                                               const int* pair_t, ushort_t* hidden) {
  __shared__ ushort_t As[2][8192];
  __shared__ ushort_t Bs[2][8192];
  __shared__ int pt[128];
  int sg = blockIdx.x >> 2, nt = blockIdx.x & 3;
  int e = ctrl[16 + sg];
  if (e < 0) return;
  int t = threadIdx.x;
  if (t < 128) pt[t] = pair_t[sg * 128 + t];
  __syncthreads();
  int n0 = nt * 128;
  const ushort_t* Bbase = W1t + (size_t)e * HH * RR;
  int lane = t & 63, wave = t >> 6;
  int wr = wave >> 1, wc = wave & 1;
  int ln = lane & 15, hi = lane >> 4;

  f32x4 acc[4][4];
  #pragma unroll
  for (int i = 0; i < 4; ++i)
    #pragma unroll
    for (int j = 0; j < 4; ++j) acc[i][j] = (f32x4){0.f, 0.f, 0.f, 0.f};

  #pragma unroll
  for (int u = 0; u < 4; ++u) {
    int idx = u * 256 + t;
    gll16(zb + (size_t)pt[idx >> 3] * RR + (idx & 7) * 8, &As[0][idx * 8]);
    gll16(Bbase + (size_t)(n0 + (idx >> 3)) * RR + (idx & 7) * 8, &Bs[0][idx * 8]);
  }
  __syncthreads();
  for (int s = 0; s < 4; ++s) {
    int cb = s & 1, xb = cb ^ 1;
    if (s < 3) {
      int k1 = (s + 1) * 64;
      #pragma unroll
      for (int u = 0; u < 4; ++u) {
        int idx = u * 256 + t;
        gll16(zb + (size_t)pt[idx >> 3] * RR + k1 + (idx & 7) * 8, &As[xb][idx * 8]);
        gll16(Bbase + (size_t)(n0 + (idx >> 3)) * RR + k1 + (idx & 7) * 8, &Bs[xb][idx * 8]);
      }
    }
    GEMM_COMPUTE(As[cb], Bs[cb]);
    __syncthreads();
  }
  #pragma unroll
  for (int i = 0; i < 4; ++i)
    #pragma unroll
    for (int j = 0; j < 4; ++j)
      #pragma unroll
      for (int r = 0; r < 4; ++r) {
        int pl = wr * 64 + i * 16 + hi * 4 + r;
        int col = n0 + wc * 64 + j * 16 + ln;
        float v = acc[i][j][r] + b1[e * HH + col];
        float g = 0.5f * v * (1.f + erff(v * 0.70710678118654752f));
        hidden[(size_t)(sg * 128 + pl) * HH + col] = f2bf(g);
      }
}

// ---------------- e2: zfin += 0.25*w*(hidden @ W2[e] + b2) -----------------
__global__ __launch_bounds__(256, 2) void k_e2(const ushort_t* hidden, const ushort_t* W2t,
                                               const float* b2, const int* ctrl,
                                               const int* pair_t, const float* pair_w,
                                               float* zfin) {
  __shared__ ushort_t As[2][8192];
  __shared__ ushort_t Bs[2][8192];
  __shared__ int pt[128];
  __shared__ float pw[128];
  int sg = blockIdx.x >> 1, nt = blockIdx.x & 1;
  int e = ctrl[16 + sg];
  if (e < 0) return;
  int t = threadIdx.x;
  if (t < 128) { pt[t] = pair_t[sg * 128 + t]; pw[t] = pair_w[sg * 128 + t]; }
  __syncthreads();
  int n0 = nt * 128;
  const ushort_t* Abase = hidden + (size_t)sg * 128 * HH;
  const ushort_t* Bbase = W2t + (size_t)e * RR * HH;
  int lane = t & 63, wave = t >> 6;
  int wr = wave >> 1, wc = wave & 1;
  int ln = lane & 15, hi = lane >> 4;

  f32x4 acc[4][4];
  #pragma unroll
  for (int i = 0; i < 4; ++i)
    #pragma unroll
    for (int j = 0; j < 4; ++j) acc[i][j] = (f32x4){0.f, 0.f, 0.f, 0.f};

  #pragma unroll
  for (int u = 0; u < 4; ++u) {
    int idx = u * 256 + t;
    gll16(Abase + (size_t)(idx >> 3) * HH + (idx & 7) * 8, &As[0][idx * 8]);
    gll16(Bbase + (size_t)(n0 + (idx >> 3)) * HH + (idx & 7) * 8, &Bs[0][idx * 8]);
  }
  __syncthreads();
  for (int s = 0; s < 8; ++s) {
    int cb = s & 1, xb = cb ^ 1;
    if (s < 7) {
      int k1 = (s + 1) * 64;
      #pragma unroll
      for (int u = 0; u < 4; ++u) {
        int idx = u * 256 + t;
        gll16(Abase + (size_t)(idx >> 3) * HH + k1 + (idx & 7) * 8, &As[xb][idx * 8]);
        gll16(Bbase + (size_t)(n0 + (idx >> 3)) * HH + k1 + (idx & 7) * 8, &Bs[xb][idx * 8]);
      }
    }
    GEMM_COMPUTE(As[cb], Bs[cb]);
    __syncthreads();
  }
  #pragma unroll
  for (int i = 0; i < 4; ++i)
    #pragma unroll
    for (int j = 0; j < 4; ++j)
      #pragma unroll
      for (int r = 0; r < 4; ++r) {
        int pl = wr * 64 + i * 16 + hi * 4 + r;
        float wv = pw[pl];
        if (wv != 0.f) {
          int col = n0 + wc * 64 + j * 16 + ln;
          float v = acc[i][j][r] + b2[e * RR + col];
          atomicAdd(&zfin[(size_t)pt[pl] * RR + col], 0.25f * wv * v);
        }
      }
}

// ---------------- final: zb2 = bf16(zfin); p_halt = sigmoid(zfin.Uh + bh) --
__global__ __launch_bounds__(256) void k_final(const float* zfin, const float* Uh,
                                               const float* bh, ushort_t* zb2, float* phalt) {
  __shared__ float luh[256];
  int t = threadIdx.x;
  if (t < 64) ((f32x4*)luh)[t] = ((const f32x4*)Uh)[t];
  __syncthreads();
  int tok = blockIdx.x * 64 + (t >> 2), q = t & 3;
  const f32x4* z4 = (const f32x4*)(zfin + (size_t)tok * RR + q * 64);
  ushort_t* o = zb2 + (size_t)tok * RR + q * 64;
  float acc = 0.f;
  #pragma unroll
  for (int it = 0; it < 16; ++it) {
    f32x4 v = z4[it];
    f32x4 u = ((const f32x4*)luh)[q * 16 + it];
    acc += v.x * u.x + v.y * u.y + v.z * u.z + v.w * u.w;
    u16x4 pk;
    pk[0] = f2bf(v.x); pk[1] = f2bf(v.y); pk[2] = f2bf(v.z); pk[3] = f2bf(v.w);
    *(u16x4*)(o + it * 4) = pk;
  }
  acc += __shfl_xor(acc, 1, 64);
  acc += __shfl_xor(acc, 2, 64);
  if (q == 0) phalt[tok] = 1.f / (1.f + expf(-(acc + bh[0])));
}

// ---------------- gemm_u: h_new[T][D] = zb2 @ U ----------------------------
__global__ __launch_bounds__(256, 2) void k_gemm_u(const ushort_t* zb2, const ushort_t* Ut,
                                                   float* outp) {
  __shared__ ushort_t As[2][8192];
  __shared__ ushort_t Bs[2][8192];
  int hw = blockIdx.x;
  int bid = (hw & 7) * 256 + (hw >> 3);    // XCD swizzle (2048 = 8*256)
  int mt = bid >> 4, nt = bid & 15;
  int m0 = mt * 128, n0 = nt * 128;
  int t = threadIdx.x;
  int lane = t & 63, wave = t >> 6;
  int wr = wave >> 1, wc = wave & 1;
  int ln = lane & 15, hi = lane >> 4;

  f32x4 acc[4][4];
  #pragma unroll
  for (int i = 0; i < 4; ++i)
    #pragma unroll
    for (int j = 0; j < 4; ++j) acc[i][j] = (f32x4){0.f, 0.f, 0.f, 0.f};

  #pragma unroll
  for (int u = 0; u < 4; ++u) {
    int idx = u * 256 + t;
    gll16(zb2 + (size_t)(m0 + (idx >> 3)) * RR + (idx & 7) * 8, &As[0][idx * 8]);
    gll16(Ut + (size_t)(n0 + (idx >> 3)) * RR + (idx & 7) * 8, &Bs[0][idx * 8]);
  }
  __syncthreads();
  for (int s = 0; s < 4; ++s) {
    int cb = s & 1, xb = cb ^ 1;
    if (s < 3) {
      int k1 = (s + 1) * 64;
      #pragma unroll
      for (int u = 0; u < 4; ++u) {
        int idx = u * 256 + t;
        gll16(zb2 + (size_t)(m0 + (idx >> 3)) * RR + k1 + (idx & 7) * 8, &As[xb][idx * 8]);
        gll16(Ut + (size_t)(n0 + (idx >> 3)) * RR + k1 + (idx & 7) * 8, &Bs[xb][idx * 8]);
      }
    }
    GEMM_COMPUTE(As[cb], Bs[cb]);
    __syncthreads();
  }
  #pragma unroll
  for (int i = 0; i < 4; ++i)
    #pragma unroll
    for (int j = 0; j < 4; ++j)
      #pragma unroll
      for (int r = 0; r < 4; ++r) {
        int row = m0 + wr * 64 + i * 16 + hi * 4 + r;
        int col = n0 + wc * 64 + j * 16 + ln;
        outp[(size_t)row * DD + col] = acc[i][j][r];
      }
}

// ---------------------------------------------------------------------------
extern "C" void kernel_launch(void* const* d_in, const int* in_sizes, int n_in,
                              void* d_out, int out_size, void* d_ws, size_t ws_size,
                              hipStream_t stream) {
  (void)in_sizes; (void)n_in; (void)out_size;
  const float* h  = (const float*)d_in[0];
  const float* V  = (const float*)d_in[1];
  const float* U  = (const float*)d_in[2];
  const float* Wr = (const float*)d_in[3];
  const float* br = (const float*)d_in[4];
  const float* W1 = (const float*)d_in[5];
  const float* b1 = (const float*)d_in[6];
  const float* W2 = (const float*)d_in[7];
  const float* b2 = (const float*)d_in[8];
  const float* Wh = (const float*)d_in[9];
  const float* bh = (const float*)d_in[10];
  float* outp = (float*)d_out;
  char* w = (char*)d_ws;

  constexpr size_t OFF_VT   = 0;
  constexpr size_t OFF_UT   = 1048576;
  constexpr size_t OFF_W1T  = 2097152;
  constexpr size_t OFF_W2T  = 4194304;
  constexpr size_t OFF_VEFF = 6291456;
  constexpr size_t OFF_UHV  = 6356992;
  constexpr size_t OFF_ZB   = 6358016;
  constexpr size_t OFF_ZFIN = 14746624;
  constexpr size_t OFF_ZB2  = 31523840;
  constexpr size_t OFF_HID  = 39912448;
  constexpr size_t OFF_TOPI = 74515456;
  constexpr size_t OFF_TOPW = 74646528;
  constexpr size_t OFF_CTRL = 74777600;
  constexpr size_t OFF_PT   = 74781696;
  constexpr size_t OFF_PW   = 74916864;
  constexpr size_t WS_NEED  = 75052032;
  if (ws_size < WS_NEED) return;

  ushort_t* Vt    = (ushort_t*)(w + OFF_VT);
  ushort_t* Ut    = (ushort_t*)(w + OFF_UT);
  ushort_t* W1t   = (ushort_t*)(w + OFF_W1T);
  ushort_t* W2t   = (ushort_t*)(w + OFF_W2T);
  float*    Veff  = (float*)(w + OFF_VEFF);
  float*    Uh    = (float*)(w + OFF_UHV);
  ushort_t* zb    = (ushort_t*)(w + OFF_ZB);
  float*    zfin  = (float*)(w + OFF_ZFIN);
  ushort_t* zb2   = (ushort_t*)(w + OFF_ZB2);
  ushort_t* hidden= (ushort_t*)(w + OFF_HID);
  int*      topi  = (int*)(w + OFF_TOPI);
  float*    topw  = (float*)(w + OFF_TOPW);
  int*      ctrl  = (int*)(w + OFF_CTRL);
  int*      pair_t= (int*)(w + OFF_PT);
  float*    pair_w= (float*)(w + OFF_PW);

  hipMemsetAsync(w + OFF_CTRL, 0, WS_NEED - OFF_CTRL, stream);

  k_prep<<<12288, 256, 0, stream>>>(V, U, W1, W2, Vt, Ut, W1t, W2t);
  k_veff<<<64, 256, 0, stream>>>(V, Wr, Veff);
  k_uh<<<64, 256, 0, stream>>>(U, Wh, Uh);
  k_router<<<512, 256, 0, stream>>>(h, Veff, br, topi, topw, ctrl);
  k_bases<<<1, 64, 0, stream>>>(ctrl);
  k_scatter<<<128, 256, 0, stream>>>(topi, topw, ctrl, pair_t, pair_w);
  k_gemm_z<<<256, 256, 0, stream>>>(h, Vt, zb, zfin);
  k_e1<<<NSEG_MAX * 4, 256, 0, stream>>>(zb, W1t, b1, ctrl, pair_t, hidden);
  k_e2<<<NSEG_MAX * 2, 256, 0, stream>>>(hidden, W2t, b2, ctrl, pair_t, pair_w, zfin);
  k_final<<<256, 256, 0, stream>>>(zfin, Uh, bh, zb2, outp + (size_t)TK * DD);
  k_gemm_u<<<2048, 256, 0, stream>>>(zb2, Ut, outp);
}

// Round 2
// 245.617 us; speedup vs baseline: 1.3900x; 1.3900x over previous
//
#include <hip/hip_runtime.h>
#include <stdint.h>
#include <math.h>

#define TK 16384
#define DD 2048
#define RR 256
#define EE 8
#define HH 512
#define NSEG_MAX 264
#define NPAIR_MAX (NSEG_MAX * 128)

typedef __attribute__((ext_vector_type(4))) float f32x4;
typedef __attribute__((ext_vector_type(8))) short s16x8;
typedef __attribute__((ext_vector_type(8))) unsigned short u16x8;
typedef __attribute__((ext_vector_type(4))) unsigned short u16x4;
typedef unsigned short ushort_t;

__device__ inline unsigned short f2bf(float f) {
  union { float f; unsigned u; } v; v.f = f;
  unsigned r = v.u + 0x7fffu + ((v.u >> 16) & 1u);
  return (unsigned short)(r >> 16);
}
__device__ inline float bf2f(ushort_t u) {
  union { unsigned u; float f; } v; v.u = ((unsigned)u) << 16; return v.f;
}

__device__ inline void gll16(const void* g, void* l) {
  __builtin_amdgcn_global_load_lds(
      (const __attribute__((address_space(1))) void*)g,
      (__attribute__((address_space(3))) void*)l, 16, 0, 0);
}

__device__ inline u16x8 pack8(f32x4 a, f32x4 b) {
  u16x8 r;
  r[0] = f2bf(a.x); r[1] = f2bf(a.y); r[2] = f2bf(a.z); r[3] = f2bf(a.w);
  r[4] = f2bf(b.x); r[5] = f2bf(b.y); r[6] = f2bf(b.z); r[7] = f2bf(b.w);
  return r;
}

// ---------------- tiled transpose: src fp32 [nr][nc] -> dst bf16 [nc][nr] ---
__global__ __launch_bounds__(256) void k_tr(const float* __restrict__ src,
                                            ushort_t* __restrict__ dst,
                                            int nr, int nc) {
  __shared__ float tile[32][33];
  int s = blockIdx.z;
  src += (size_t)s * nr * nc;
  dst += (size_t)s * nr * nc;
  int tx = threadIdx.x & 31, ty = threadIdx.x >> 5;
  int c0 = blockIdx.x * 32, r0 = blockIdx.y * 32;
  #pragma unroll
  for (int i = 0; i < 32; i += 8)
    tile[ty + i][tx] = src[(size_t)(r0 + ty + i) * nc + c0 + tx];
  __syncthreads();
  #pragma unroll
  for (int i = 0; i < 32; i += 8)
    dst[(size_t)(c0 + ty + i) * nr + r0 + tx] = f2bf(tile[tx][ty + i]);
}

// ---------------- VeffT[e][d] = sum_r V[d][r]*Wr[r][e]  (fp32 routing matrix)
__global__ __launch_bounds__(256) void k_veff(const float* __restrict__ V,
                                              const float* __restrict__ Wr,
                                              float* __restrict__ VeffT) {
  __shared__ float lwr[RR * EE];
  int t = threadIdx.x;
  #pragma unroll
  for (int i = 0; i < 8; ++i) lwr[i * 256 + t] = Wr[i * 256 + t];
  __syncthreads();
  int d = blockIdx.x * 256 + t;
  float a[8] = {0, 0, 0, 0, 0, 0, 0, 0};
  const float* vrow = V + (size_t)d * RR;
  for (int r = 0; r < RR; r += 4) {
    f32x4 v = *(const f32x4*)(vrow + r);
    #pragma unroll
    for (int e = 0; e < 8; ++e)
      a[e] += v.x * lwr[r * 8 + e] + v.y * lwr[(r + 1) * 8 + e] +
              v.z * lwr[(r + 2) * 8 + e] + v.w * lwr[(r + 3) * 8 + e];
  }
  #pragma unroll
  for (int e = 0; e < 8; ++e) VeffT[(size_t)e * DD + d] = a[e];
}

// ---------------- Uh[r] = sum_d U[r][d]*Wh[d] ------------------------------
__global__ void k_uh(const float* U, const float* Wh, float* Uh) {
  int wave = threadIdx.x >> 6, lane = threadIdx.x & 63;
  int r = blockIdx.x * 4 + wave;
  const f32x4* u4 = (const f32x4*)(U + (size_t)r * DD);
  const f32x4* w4 = (const f32x4*)Wh;
  float acc = 0.f;
  #pragma unroll
  for (int it = 0; it < 8; ++it) {
    f32x4 a = u4[it * 64 + lane], b = w4[it * 64 + lane];
    acc += a.x * b.x + a.y * b.y + a.z * b.z + a.w * b.w;
  }
  #pragma unroll
  for (int o = 32; o; o >>= 1) acc += __shfl_down(acc, o, 64);
  if (lane == 0) Uh[r] = acc;
}

// ---------------- fused front: z=h@V (bf16 MFMA) + exact-fp32 router --------
// tile 32 rows x 256 cols, K-step 64, 4 waves (each 32x64), grid 512.
__global__ __launch_bounds__(256, 2) void k_front(
    const float* __restrict__ h, const ushort_t* __restrict__ Vt,
    const float* __restrict__ VeffT, const float* __restrict__ br,
    ushort_t* __restrict__ zb, int* __restrict__ topi, float* __restrict__ topw,
    int* __restrict__ ctrl) {
  __shared__ ushort_t As[2][32 * 72];     // padded stride 72: frag reads 2-way
  __shared__ ushort_t Bs[2][256 * 64];
  __shared__ float Vs[2][8 * 64];         // VeffT chunk [e][64]
  __shared__ int lcnt[8];
  int t = threadIdx.x;
  int m0 = blockIdx.x * 32;
  int lane = t & 63, wave = t >> 6;
  int ln = lane & 15, hi = lane >> 4;
  int arow = t >> 3, koff = (t & 7) * 8;
  const float* aptr = h + (size_t)(m0 + arow) * DD + koff;
  if (t < 8) lcnt[t] = 0;

  f32x4 acc[2][4];
  #pragma unroll
  for (int i = 0; i < 2; ++i)
    #pragma unroll
    for (int j = 0; j < 4; ++j) acc[i][j] = (f32x4){0.f, 0.f, 0.f, 0.f};
  float racc[8] = {0, 0, 0, 0, 0, 0, 0, 0};

  f32x4 pc0, pc1, pn0, pn1;
  {  // prologue k=0
    pc0 = ((const f32x4*)aptr)[0];
    pc1 = ((const f32x4*)aptr)[1];
    #pragma unroll
    for (int u = 0; u < 8; ++u) {
      int idx = u * 256 + t;
      gll16(Vt + (size_t)(idx >> 3) * DD + (idx & 7) * 8, &Bs[0][idx * 8]);
    }
    if (t < 128) gll16(VeffT + (size_t)(t >> 4) * DD + (t & 15) * 4, &Vs[0][t * 4]);
    *(u16x8*)&As[0][arow * 72 + koff] = pack8(pc0, pc1);
  }
  __syncthreads();

  for (int s = 0; s < 32; ++s) {
    int cb = s & 1, xb = cb ^ 1;
    int k1 = (s + 1) * 64;
    if (s < 31) {
      pn0 = ((const f32x4*)(aptr + k1))[0];
      pn1 = ((const f32x4*)(aptr + k1))[1];
      #pragma unroll
      for (int u = 0; u < 8; ++u) {
        int idx = u * 256 + t;
        gll16(Vt + (size_t)(idx >> 3) * DD + k1 + (idx & 7) * 8, &Bs[xb][idx * 8]);
      }
      if (t < 128) gll16(VeffT + (size_t)(t >> 4) * DD + k1 + (t & 15) * 4, &Vs[xb][t * 4]);
    }
    // exact-fp32 router partial on current chunk (h fp32 in regs, Veff in LDS)
    {
      const f32x4* vsb = (const f32x4*)&Vs[cb][0];
      #pragma unroll
      for (int e = 0; e < 8; ++e) {
        f32x4 v0 = vsb[(e * 64 + koff) >> 2];
        f32x4 v1 = vsb[((e * 64 + koff) >> 2) + 1];
        racc[e] += pc0.x * v0.x + pc0.y * v0.y + pc0.z * v0.z + pc0.w * v0.w +
                   pc1.x * v1.x + pc1.y * v1.y + pc1.z * v1.z + pc1.w * v1.w;
      }
    }
    #pragma unroll
    for (int ks = 0; ks < 2; ++ks) {
      s16x8 af[2], bq[4];
      #pragma unroll
      for (int i = 0; i < 2; ++i)
        af[i] = *(const s16x8*)&As[cb][(i * 16 + ln) * 72 + ks * 32 + hi * 8];
      #pragma unroll
      for (int j = 0; j < 4; ++j)
        bq[j] = *(const s16x8*)&Bs[cb][(wave * 64 + j * 16 + ln) * 64 + ks * 32 + hi * 8];
      #pragma unroll
      for (int i = 0; i < 2; ++i)
        #pragma unroll
        for (int j = 0; j < 4; ++j)
          acc[i][j] = __builtin_amdgcn_mfma_f32_16x16x32_bf16(af[i], bq[j], acc[i][j], 0, 0, 0);
    }
    if (s < 31) {
      *(u16x8*)&As[xb][arow * 72 + koff] = pack8(pn0, pn1);
      pc0 = pn0; pc1 = pn1;
    }
    __syncthreads();
  }

  // epilogue: z write
  #pragma unroll
  for (int i = 0; i < 2; ++i)
    #pragma unroll
    for (int j = 0; j < 4; ++j)
      #pragma unroll
      for (int r = 0; r < 4; ++r) {
        int row = m0 + i * 16 + hi * 4 + r;
        int col = wave * 64 + j * 16 + ln;
        zb[(size_t)row * RR + col] = f2bf(acc[i][j][r]);
      }

  // router: reduce over the 8 lanes sharing a row, then top-2
  #pragma unroll
  for (int e = 0; e < 8; ++e) {
    racc[e] += __shfl_xor(racc[e], 1, 64);
    racc[e] += __shfl_xor(racc[e], 2, 64);
    racc[e] += __shfl_xor(racc[e], 4, 64);
  }
  if ((t & 7) == 0) {
    int token = m0 + arow;
    f32x4 br0 = ((const f32x4*)br)[0], br1 = ((const f32x4*)br)[1];
    float l[8] = {racc[0] + br0.x, racc[1] + br0.y, racc[2] + br0.z, racc[3] + br0.w,
                  racc[4] + br1.x, racc[5] + br1.y, racc[6] + br1.z, racc[7] + br1.w};
    float best = -1e30f; int bi = 0;
    #pragma unroll
    for (int e = 0; e < 8; ++e) if (l[e] > best) { best = l[e]; bi = e; }
    float sec = -1e30f; int si = 0;
    #pragma unroll
    for (int e = 0; e < 8; ++e) if (e != bi && l[e] > sec) { sec = l[e]; si = e; }
    float w0 = 1.f / (1.f + expf(sec - best));
    topi[token * 2 + 0] = bi; topi[token * 2 + 1] = si;
    topw[token * 2 + 0] = w0; topw[token * 2 + 1] = 1.f - w0;
    atomicAdd(&lcnt[bi], 1);
    atomicAdd(&lcnt[si], 1);
  }
  __syncthreads();
  if (t < 8) atomicAdd(&ctrl[t], lcnt[t]);
}

// ---------------- bases: padded per-expert segments -------------------------
// ctrl layout (ints): [0..7]=counts [8..15]=gcursor [16..16+264)=seg2expert
__global__ void k_bases(int* ctrl) {
  if (threadIdx.x == 0) {
    int cum = 0;
    for (int e = 0; e < 8; ++e) {
      int c = ctrl[e];
      int segs = (c + 127) >> 7;
      ctrl[8 + e] = cum;
      for (int s2 = 0; s2 < segs; ++s2) ctrl[16 + (cum >> 7) + s2] = e;
      cum += segs << 7;
    }
    for (int s2 = cum >> 7; s2 < NSEG_MAX; ++s2) ctrl[16 + s2] = -1;
  }
}

// ---------------- scatter tokens into per-expert pair lists + inverse map ---
__global__ __launch_bounds__(256) void k_scatter(const int* topi, const float* topw,
                                                 int* ctrl, int* pair_t, float* pair_w,
                                                 int* inv) {
  __shared__ int lcnt[8], lbase[8];
  int t = threadIdx.x;
  if (t < 8) lcnt[t] = 0;
  __syncthreads();
  int slot = blockIdx.x * 256 + t;
  int e = topi[slot];
  float wv = topw[slot];
  int lp = atomicAdd(&lcnt[e], 1);
  __syncthreads();
  if (t < 8) lbase[t] = atomicAdd(&ctrl[8 + t], lcnt[t]);
  __syncthreads();
  int p = lbase[e] + lp;
  pair_t[p] = slot >> 1;
  pair_w[p] = wv;
  inv[slot] = p;
}

#define GEMM_COMPUTE(AS, BS)                                                          \
  _Pragma("unroll")                                                                   \
  for (int ks = 0; ks < 2; ++ks) {                                                    \
    s16x8 af[4], bq[4];                                                               \
    _Pragma("unroll")                                                                 \
    for (int i = 0; i < 4; ++i)                                                       \
      af[i] = *(const s16x8*)&AS[(wr * 64 + i * 16 + ln) * 64 + ks * 32 + hi * 8];    \
    _Pragma("unroll")                                                                 \
    for (int j = 0; j < 4; ++j)                                                       \
      bq[j] = *(const s16x8*)&BS[(wc * 64 + j * 16 + ln) * 64 + ks * 32 + hi * 8];    \
    _Pragma("unroll")                                                                 \
    for (int i = 0; i < 4; ++i)                                                       \
      _Pragma("unroll")                                                               \
      for (int j = 0; j < 4; ++j)                                                     \
        acc[i][j] = __builtin_amdgcn_mfma_f32_16x16x32_bf16(af[i], bq[j], acc[i][j], 0, 0, 0); \
  }

// ---------------- e1: hidden = gelu(gather(zb) @ W1[e] + b1) ---------------
__global__ __launch_bounds__(256, 2) void k_e1(const ushort_t* zb, const ushort_t* W1t,
                                               const float* b1, const int* ctrl,
                                               const int* pair_t, ushort_t* hidden) {
  __shared__ ushort_t As[2][8192];
  __shared__ ushort_t Bs[2][8192];
  __shared__ int pt[128];
  int sg = blockIdx.x >> 2, nt = blockIdx.x & 3;
  int e = ctrl[16 + sg];
  if (e < 0) return;
  int t = threadIdx.x;
  if (t < 128) pt[t] = pair_t[sg * 128 + t];
  __syncthreads();
  int n0 = nt * 128;
  const ushort_t* Bbase = W1t + (size_t)e * HH * RR;
  int lane = t & 63, wave = t >> 6;
  int wr = wave >> 1, wc = wave & 1;
  int ln = lane & 15, hi = lane >> 4;

  f32x4 acc[4][4];
  #pragma unroll
  for (int i = 0; i < 4; ++i)
    #pragma unroll
    for (int j = 0; j < 4; ++j) acc[i][j] = (f32x4){0.f, 0.f, 0.f, 0.f};

  #pragma unroll
  for (int u = 0; u < 4; ++u) {
    int idx = u * 256 + t;
    gll16(zb + (size_t)pt[idx >> 3] * RR + (idx & 7) * 8, &As[0][idx * 8]);
    gll16(Bbase + (size_t)(n0 + (idx >> 3)) * RR + (idx & 7) * 8, &Bs[0][idx * 8]);
  }
  __syncthreads();
  for (int s = 0; s < 4; ++s) {
    int cb = s & 1, xb = cb ^ 1;
    if (s < 3) {
      int k1 = (s + 1) * 64;
      #pragma unroll
      for (int u = 0; u < 4; ++u) {
        int idx = u * 256 + t;
        gll16(zb + (size_t)pt[idx >> 3] * RR + k1 + (idx & 7) * 8, &As[xb][idx * 8]);
        gll16(Bbase + (size_t)(n0 + (idx >> 3)) * RR + k1 + (idx & 7) * 8, &Bs[xb][idx * 8]);
      }
    }
    GEMM_COMPUTE(As[cb], Bs[cb]);
    __syncthreads();
  }
  #pragma unroll
  for (int i = 0; i < 4; ++i)
    #pragma unroll
    for (int j = 0; j < 4; ++j)
      #pragma unroll
      for (int r = 0; r < 4; ++r) {
        int pl = wr * 64 + i * 16 + hi * 4 + r;
        int col = n0 + wc * 64 + j * 16 + ln;
        float v = acc[i][j][r] + b1[e * HH + col];
        float g = 0.5f * v * (1.f + erff(v * 0.70710678118654752f));
        hidden[(size_t)(sg * 128 + pl) * HH + col] = f2bf(g);
      }
}

// ---------------- e2: eout[p] = w_p * (hidden @ W2[e] + b2)  (bf16 stores) --
__global__ __launch_bounds__(256, 2) void k_e2(const ushort_t* hidden, const ushort_t* W2t,
                                               const float* b2, const int* ctrl,
                                               const int* pair_t, const float* pair_w,
                                               ushort_t* eout) {
  __shared__ ushort_t As[2][8192];
  __shared__ ushort_t Bs[2][8192];
  __shared__ float pw[128];
  int sg = blockIdx.x >> 1, nt = blockIdx.x & 1;
  int e = ctrl[16 + sg];
  if (e < 0) return;
  int t = threadIdx.x;
  if (t < 128) pw[t] = pair_w[sg * 128 + t];
  __syncthreads();
  int n0 = nt * 128;
  const ushort_t* Abase = hidden + (size_t)sg * 128 * HH;
  const ushort_t* Bbase = W2t + (size_t)e * RR * HH;
  int lane = t & 63, wave = t >> 6;
  int wr = wave >> 1, wc = wave & 1;
  int ln = lane & 15, hi = lane >> 4;

  f32x4 acc[4][4];
  #pragma unroll
  for (int i = 0; i < 4; ++i)
    #pragma unroll
    for (int j = 0; j < 4; ++j) acc[i][j] = (f32x4){0.f, 0.f, 0.f, 0.f};

  #pragma unroll
  for (int u = 0; u < 4; ++u) {
    int idx = u * 256 + t;
    gll16(Abase + (size_t)(idx >> 3) * HH + (idx & 7) * 8, &As[0][idx * 8]);
    gll16(Bbase + (size_t)(n0 + (idx >> 3)) * HH + (idx & 7) * 8, &Bs[0][idx * 8]);
  }
  __syncthreads();
  for (int s = 0; s < 8; ++s) {
    int cb = s & 1, xb = cb ^ 1;
    if (s < 7) {
      int k1 = (s + 1) * 64;
      #pragma unroll
      for (int u = 0; u < 4; ++u) {
        int idx = u * 256 + t;
        gll16(Abase + (size_t)(idx >> 3) * HH + k1 + (idx & 7) * 8, &As[xb][idx * 8]);
        gll16(Bbase + (size_t)(n0 + (idx >> 3)) * HH + k1 + (idx & 7) * 8, &Bs[xb][idx * 8]);
      }
    }
    GEMM_COMPUTE(As[cb], Bs[cb]);
    __syncthreads();
  }
  #pragma unroll
  for (int i = 0; i < 4; ++i)
    #pragma unroll
    for (int j = 0; j < 4; ++j)
      #pragma unroll
      for (int r = 0; r < 4; ++r) {
        int pl = wr * 64 + i * 16 + hi * 4 + r;
        int col = n0 + wc * 64 + j * 16 + ln;
        float v = acc[i][j][r] + b2[e * RR + col];
        eout[(size_t)(sg * 128 + pl) * RR + col] = f2bf(pw[pl] * v);
      }
}

// ---------------- final: z_final = 0.75*z + 0.25*(eout0+eout1);
//                  zb2 = bf16(z_final); p_halt = sigmoid(z_final.Uh + bh) ----
__global__ __launch_bounds__(256) void k_final(const ushort_t* __restrict__ zb,
                                               const ushort_t* __restrict__ eout,
                                               const int* __restrict__ inv,
                                               const float* __restrict__ Uh,
                                               const float* __restrict__ bh,
                                               ushort_t* __restrict__ zb2,
                                               float* __restrict__ phalt) {
  __shared__ float luh[256];
  int t = threadIdx.x;
  if (t < 64) ((f32x4*)luh)[t] = ((const f32x4*)Uh)[t];
  __syncthreads();
  int tok = blockIdx.x * 64 + (t >> 2), q = t & 3;
  int i0 = inv[tok * 2], i1 = inv[tok * 2 + 1];
  const u16x8* z8 = (const u16x8*)(zb + (size_t)tok * RR + q * 64);
  const u16x8* ea = (const u16x8*)(eout + (size_t)i0 * RR + q * 64);
  const u16x8* eb = (const u16x8*)(eout + (size_t)i1 * RR + q * 64);
  ushort_t* o = zb2 + (size_t)tok * RR + q * 64;
  float acc = 0.f;
  #pragma unroll
  for (int it = 0; it < 8; ++it) {
    u16x8 zv = z8[it], av = ea[it], bv = eb[it];
    u16x8 pk;
    #pragma unroll
    for (int j = 0; j < 8; ++j) {
      float zf = 0.75f * bf2f(zv[j]) + 0.25f * (bf2f(av[j]) + bf2f(bv[j]));
      acc += zf * luh[q * 64 + it * 8 + j];
      pk[j] = f2bf(zf);
    }
    *(u16x8*)(o + it * 8) = pk;
  }
  acc += __shfl_xor(acc, 1, 64);
  acc += __shfl_xor(acc, 2, 64);
  if (q == 0) phalt[tok] = 1.f / (1.f + expf(-(acc + bh[0])));
}

// ---------------- gemm_u: h_new[T][D] = zb2 @ U ----------------------------
__global__ __launch_bounds__(256, 2) void k_gemm_u(const ushort_t* zb2, const ushort_t* Ut,
                                                   float* outp) {
  __shared__ ushort_t As[2][8192];
  __shared__ ushort_t Bs[2][8192];
  int hw = blockIdx.x;
  int bid = (hw & 7) * 256 + (hw >> 3);    // XCD swizzle (2048 = 8*256)
  int mt = bid >> 4, nt = bid & 15;
  int m0 = mt * 128, n0 = nt * 128;
  int t = threadIdx.x;
  int lane = t & 63, wave = t >> 6;
  int wr = wave >> 1, wc = wave & 1;
  int ln = lane & 15, hi = lane >> 4;

  f32x4 acc[4][4];
  #pragma unroll
  for (int i = 0; i < 4; ++i)
    #pragma unroll
    for (int j = 0; j < 4; ++j) acc[i][j] = (f32x4){0.f, 0.f, 0.f, 0.f};

  #pragma unroll
  for (int u = 0; u < 4; ++u) {
    int idx = u * 256 + t;
    gll16(zb2 + (size_t)(m0 + (idx >> 3)) * RR + (idx & 7) * 8, &As[0][idx * 8]);
    gll16(Ut + (size_t)(n0 + (idx >> 3)) * RR + (idx & 7) * 8, &Bs[0][idx * 8]);
  }
  __syncthreads();
  for (int s = 0; s < 4; ++s) {
    int cb = s & 1, xb = cb ^ 1;
    if (s < 3) {
      int k1 = (s + 1) * 64;
      #pragma unroll
      for (int u = 0; u < 4; ++u) {
        int idx = u * 256 + t;
        gll16(zb2 + (size_t)(m0 + (idx >> 3)) * RR + k1 + (idx & 7) * 8, &As[xb][idx * 8]);
        gll16(Ut + (size_t)(n0 + (idx >> 3)) * RR + k1 + (idx & 7) * 8, &Bs[xb][idx * 8]);
      }
    }
    GEMM_COMPUTE(As[cb], Bs[cb]);
    __syncthreads();
  }
  #pragma unroll
  for (int i = 0; i < 4; ++i)
    #pragma unroll
    for (int j = 0; j < 4; ++j)
      #pragma unroll
      for (int r = 0; r < 4; ++r) {
        int row = m0 + wr * 64 + i * 16 + hi * 4 + r;
        int col = n0 + wc * 64 + j * 16 + ln;
        outp[(size_t)row * DD + col] = acc[i][j][r];
      }
}

// ---------------------------------------------------------------------------
extern "C" void kernel_launch(void* const* d_in, const int* in_sizes, int n_in,
                              void* d_out, int out_size, void* d_ws, size_t ws_size,
                              hipStream_t stream) {
  (void)in_sizes; (void)n_in; (void)out_size;
  const float* h  = (const float*)d_in[0];
  const float* V  = (const float*)d_in[1];
  const float* U  = (const float*)d_in[2];
  const float* Wr = (const float*)d_in[3];
  const float* br = (const float*)d_in[4];
  const float* W1 = (const float*)d_in[5];
  const float* b1 = (const float*)d_in[6];
  const float* W2 = (const float*)d_in[7];
  const float* b2 = (const float*)d_in[8];
  const float* Wh = (const float*)d_in[9];
  const float* bh = (const float*)d_in[10];
  float* outp = (float*)d_out;
  char* w = (char*)d_ws;

  constexpr size_t OFF_VT    = 0;          // 1 MB   Vt   [256][2048] bf16
  constexpr size_t OFF_UT    = 1048576;    // 1 MB   Ut   [2048][256] bf16
  constexpr size_t OFF_W1T   = 2097152;    // 2 MB   W1t  [8][512][256] bf16
  constexpr size_t OFF_W2T   = 4194304;    // 2 MB   W2t  [8][256][512] bf16
  constexpr size_t OFF_VEFFT = 6291456;    // 64 KB  VeffT [8][2048] f32
  constexpr size_t OFF_UHV   = 6356992;    // 4 KB   Uh [256] f32
  constexpr size_t OFF_TOPI  = 6361088;    // 128 KB
  constexpr size_t OFF_TOPW  = 6492160;    // 128 KB
  constexpr size_t OFF_INV   = 6623232;    // 128 KB
  constexpr size_t OFF_CTRL  = 6754304;    // 4 KB
  constexpr size_t OFF_PT    = 6758400;    // 132 KB
  constexpr size_t OFF_PW    = 6893568;    // 132 KB
  constexpr size_t OFF_ZB    = 7028736;    // 8 MB   zb [16384][256] bf16
  constexpr size_t OFF_EOUT  = 15417344;   // 16.5MB eout [33792][256] bf16
  constexpr size_t OFF_HID   = 32718848;   // 33 MB  hidden [33792][512] bf16
  constexpr size_t OFF_ZB2   = OFF_HID;    // aliases hidden (dead after e2)
  constexpr size_t WS_NEED   = 67321856;
  if (ws_size < WS_NEED) return;

  ushort_t* Vt    = (ushort_t*)(w + OFF_VT);
  ushort_t* Ut    = (ushort_t*)(w + OFF_UT);
  ushort_t* W1t   = (ushort_t*)(w + OFF_W1T);
  ushort_t* W2t   = (ushort_t*)(w + OFF_W2T);
  float*    VeffT = (float*)(w + OFF_VEFFT);
  float*    Uh    = (float*)(w + OFF_UHV);
  int*      topi  = (int*)(w + OFF_TOPI);
  float*    topw  = (float*)(w + OFF_TOPW);
  int*      inv   = (int*)(w + OFF_INV);
  int*      ctrl  = (int*)(w + OFF_CTRL);
  int*      pair_t= (int*)(w + OFF_PT);
  float*    pair_w= (float*)(w + OFF_PW);
  ushort_t* zb    = (ushort_t*)(w + OFF_ZB);
  ushort_t* eout  = (ushort_t*)(w + OFF_EOUT);
  ushort_t* hidden= (ushort_t*)(w + OFF_HID);
  ushort_t* zb2   = (ushort_t*)(w + OFF_ZB2);

  // zero ctrl + pair lists (padding slots must have pt=0, pw=0)
  hipMemsetAsync(w + OFF_CTRL, 0, OFF_ZB - OFF_CTRL, stream);

  k_tr<<<dim3(8, 64, 1), 256, 0, stream>>>(V, Vt, 2048, 256);
  k_tr<<<dim3(64, 8, 1), 256, 0, stream>>>(U, Ut, 256, 2048);
  k_tr<<<dim3(16, 8, 8), 256, 0, stream>>>(W1, W1t, 256, 512);
  k_tr<<<dim3(8, 16, 8), 256, 0, stream>>>(W2, W2t, 512, 256);
  k_veff<<<8, 256, 0, stream>>>(V, Wr, VeffT);
  k_uh<<<64, 256, 0, stream>>>(U, Wh, Uh);
  k_front<<<512, 256, 0, stream>>>(h, Vt, VeffT, br, zb, topi, topw, ctrl);
  k_bases<<<1, 64, 0, stream>>>(ctrl);
  k_scatter<<<128, 256, 0, stream>>>(topi, topw, ctrl, pair_t, pair_w, inv);
  k_e1<<<NSEG_MAX * 4, 256, 0, stream>>>(zb, W1t, b1, ctrl, pair_t, hidden);
  k_e2<<<NSEG_MAX * 2, 256, 0, stream>>>(hidden, W2t, b2, ctrl, pair_t, pair_w, eout);
  k_final<<<256, 256, 0, stream>>>(zb, eout, inv, Uh, bh, zb2, outp + (size_t)TK * DD);
  k_gemm_u<<<2048, 256, 0, stream>>>(zb2, Ut, outp);
}

// Round 4
// 224.929 us; speedup vs baseline: 1.5179x; 1.0920x over previous
//
#include <hip/hip_runtime.h>
#include <stdint.h>
#include <math.h>

#define TK 16384
#define DD 2048
#define RR 256
#define EE 8
#define HH 512
#define NSEG_MAX 264
#define NPAIR_MAX (NSEG_MAX * 128)

typedef __attribute__((ext_vector_type(4))) float f32x4;
typedef __attribute__((ext_vector_type(8))) short s16x8;
typedef __attribute__((ext_vector_type(8))) unsigned short u16x8;
typedef __attribute__((ext_vector_type(4))) unsigned u32x4;
typedef unsigned short ushort_t;

__device__ inline unsigned short f2bf(float f) {
  union { float f; unsigned u; } v; v.f = f;
  unsigned r = v.u + 0x7fffu + ((v.u >> 16) & 1u);
  return (unsigned short)(r >> 16);
}
__device__ inline float bf2f(ushort_t u) {
  union { unsigned u; float f; } v; v.u = ((unsigned)u) << 16; return v.f;
}

__device__ inline void gll16(const void* g, void* l) {
  __builtin_amdgcn_global_load_lds(
      (const __attribute__((address_space(1))) void*)g,
      (__attribute__((address_space(3))) void*)l, 16, 0, 0);
}

__device__ inline u16x8 pack8(f32x4 a, f32x4 b) {
  u16x8 r;
  r[0] = f2bf(a.x); r[1] = f2bf(a.y); r[2] = f2bf(a.z); r[3] = f2bf(a.w);
  r[4] = f2bf(b.x); r[5] = f2bf(b.y); r[6] = f2bf(b.z); r[7] = f2bf(b.w);
  return r;
}

// ---------------- fused prep: 4 transposes + VeffT + Uh ---------------------
// blocks: [0,512) V->Vt, [512,1024) U->Ut, [1024,2048) W1->W1t,
//         [2048,3072) W2->W2t, [3072,3080) VeffT, [3080,3144) Uh
__global__ __launch_bounds__(256) void k_prep(
    const float* __restrict__ V, const float* __restrict__ U,
    const float* __restrict__ W1, const float* __restrict__ W2,
    const float* __restrict__ Wr, const float* __restrict__ Wh,
    ushort_t* __restrict__ Vt, ushort_t* __restrict__ Ut,
    ushort_t* __restrict__ W1t, ushort_t* __restrict__ W2t,
    float* __restrict__ VeffT, float* __restrict__ Uh) {
  __shared__ float sm[2112];
  int b = blockIdx.x, t = threadIdx.x;
  if (b < 3072) {
    const float* src; ushort_t* dst; int nr, nc, c0, r0;
    if (b < 512)       { src = V; dst = Vt; nr = 2048; nc = 256;
                         c0 = (b & 7) * 32; r0 = (b >> 3) * 32; }
    else if (b < 1024) { int bx = b - 512; src = U; dst = Ut; nr = 256; nc = 2048;
                         c0 = (bx & 63) * 32; r0 = (bx >> 6) * 32; }
    else if (b < 2048) { int bx = b - 1024; int s = bx >> 7; bx &= 127;
                         src = W1 + (size_t)s * 131072; dst = W1t + (size_t)s * 131072;
                         nr = 256; nc = 512; c0 = (bx & 15) * 32; r0 = (bx >> 4) * 32; }
    else               { int bx = b - 2048; int s = bx >> 7; bx &= 127;
                         src = W2 + (size_t)s * 131072; dst = W2t + (size_t)s * 131072;
                         nr = 512; nc = 256; c0 = (bx & 7) * 32; r0 = (bx >> 3) * 32; }
    int tx = t & 31, ty = t >> 5;
    #pragma unroll
    for (int i = 0; i < 32; i += 8)
      sm[(ty + i) * 33 + tx] = src[(size_t)(r0 + ty + i) * nc + c0 + tx];
    __syncthreads();
    #pragma unroll
    for (int i = 0; i < 32; i += 8)
      dst[(size_t)(c0 + ty + i) * nr + r0 + tx] = f2bf(sm[tx * 33 + ty + i]);
  } else if (b < 3080) {
    #pragma unroll
    for (int i = 0; i < 8; ++i) sm[i * 256 + t] = Wr[i * 256 + t];
    __syncthreads();
    int d = (b - 3072) * 256 + t;
    float a[8] = {0, 0, 0, 0, 0, 0, 0, 0};
    const float* vrow = V + (size_t)d * RR;
    for (int r = 0; r < RR; r += 4) {
      f32x4 v = *(const f32x4*)(vrow + r);
      #pragma unroll
      for (int e = 0; e < 8; ++e)
        a[e] += v.x * sm[r * 8 + e] + v.y * sm[(r + 1) * 8 + e] +
                v.z * sm[(r + 2) * 8 + e] + v.w * sm[(r + 3) * 8 + e];
    }
    #pragma unroll
    for (int e = 0; e < 8; ++e) VeffT[(size_t)e * DD + d] = a[e];
  } else {
    int wave = t >> 6, lane = t & 63;
    int r = (b - 3080) * 4 + wave;
    const f32x4* u4 = (const f32x4*)(U + (size_t)r * DD);
    const f32x4* w4 = (const f32x4*)Wh;
    float acc = 0.f;
    #pragma unroll
    for (int it = 0; it < 8; ++it) {
      f32x4 a = u4[it * 64 + lane], bb = w4[it * 64 + lane];
      acc += a.x * bb.x + a.y * bb.y + a.z * bb.z + a.w * bb.w;
    }
    #pragma unroll
    for (int o = 32; o; o >>= 1) acc += __shfl_down(acc, o, 64);
    if (lane == 0) Uh[r] = acc;
  }
}

// ---------------- fused front (round-2 known-good): z=h@V + fp32 router -----
// tile 32 rows x 256 cols, K-step 64, 4 waves (each 32x64), grid 512.
__global__ __launch_bounds__(256, 2) void k_front(
    const float* __restrict__ h, const ushort_t* __restrict__ Vt,
    const float* __restrict__ VeffT, const float* __restrict__ br,
    ushort_t* __restrict__ zb, int* __restrict__ topi, float* __restrict__ topw,
    int* __restrict__ ctrl) {
  __shared__ ushort_t As[2][32 * 72];     // padded stride 72
  __shared__ ushort_t Bs[2][256 * 64];
  __shared__ float Vs[2][512];            // VeffT chunk [8][64]
  __shared__ int lcnt[8];
  int t = threadIdx.x;
  int m0 = blockIdx.x * 32;
  int lane = t & 63, wave = t >> 6;
  int ln = lane & 15, hi = lane >> 4;
  int arow = t >> 3, koff = (t & 7) * 8;
  const float* aptr = h + (size_t)(m0 + arow) * DD + koff;
  if (t < 8) lcnt[t] = 0;

  f32x4 acc[2][4];
  #pragma unroll
  for (int i = 0; i < 2; ++i)
    #pragma unroll
    for (int j = 0; j < 4; ++j) acc[i][j] = (f32x4){0.f, 0.f, 0.f, 0.f};
  float racc[8] = {0, 0, 0, 0, 0, 0, 0, 0};

  f32x4 pc0, pc1, pn0, pn1;
  {  // prologue k=0
    pc0 = ((const f32x4*)aptr)[0];
    pc1 = ((const f32x4*)aptr)[1];
    #pragma unroll
    for (int u = 0; u < 8; ++u) {
      int idx = u * 256 + t;
      gll16(Vt + (size_t)(idx >> 3) * DD + (idx & 7) * 8, &Bs[0][idx * 8]);
    }
    if (t < 128) gll16(VeffT + (size_t)(t >> 4) * DD + (t & 15) * 4, &Vs[0][t * 4]);
    *(u16x8*)&As[0][arow * 72 + koff] = pack8(pc0, pc1);
  }
  __syncthreads();

  for (int s = 0; s < 32; ++s) {
    int cb = s & 1, xb = cb ^ 1;
    int k1 = (s + 1) * 64;
    if (s < 31) {
      pn0 = ((const f32x4*)(aptr + k1))[0];
      pn1 = ((const f32x4*)(aptr + k1))[1];
      #pragma unroll
      for (int u = 0; u < 8; ++u) {
        int idx = u * 256 + t;
        gll16(Vt + (size_t)(idx >> 3) * DD + k1 + (idx & 7) * 8, &Bs[xb][idx * 8]);
      }
      if (t < 128) gll16(VeffT + (size_t)(t >> 4) * DD + k1 + (t & 15) * 4, &Vs[xb][t * 4]);
    }
    // exact-fp32 router partial on current chunk
    {
      const f32x4* vsb = (const f32x4*)&Vs[cb][0];
      #pragma unroll
      for (int e = 0; e < 8; ++e) {
        f32x4 v0 = vsb[(e * 64 + koff) >> 2];
        f32x4 v1 = vsb[((e * 64 + koff) >> 2) + 1];
        racc[e] += pc0.x * v0.x + pc0.y * v0.y + pc0.z * v0.z + pc0.w * v0.w +
                   pc1.x * v1.x + pc1.y * v1.y + pc1.z * v1.z + pc1.w * v1.w;
      }
    }
    #pragma unroll
    for (int ks = 0; ks < 2; ++ks) {
      s16x8 af[2], bq[4];
      #pragma unroll
      for (int i = 0; i < 2; ++i)
        af[i] = *(const s16x8*)&As[cb][(i * 16 + ln) * 72 + ks * 32 + hi * 8];
      #pragma unroll
      for (int j = 0; j < 4; ++j)
        bq[j] = *(const s16x8*)&Bs[cb][(wave * 64 + j * 16 + ln) * 64 + ks * 32 + hi * 8];
      #pragma unroll
      for (int i = 0; i < 2; ++i)
        #pragma unroll
        for (int j = 0; j < 4; ++j)
          acc[i][j] = __builtin_amdgcn_mfma_f32_16x16x32_bf16(af[i], bq[j], acc[i][j], 0, 0, 0);
    }
    if (s < 31) {
      *(u16x8*)&As[xb][arow * 72 + koff] = pack8(pn0, pn1);
      pc0 = pn0; pc1 = pn1;
    }
    __syncthreads();
  }

  // z write
  #pragma unroll
  for (int i = 0; i < 2; ++i)
    #pragma unroll
    for (int j = 0; j < 4; ++j)
      #pragma unroll
      for (int r = 0; r < 4; ++r) {
        int row = m0 + i * 16 + hi * 4 + r;
        int col = wave * 64 + j * 16 + ln;
        zb[(size_t)row * RR + col] = f2bf(acc[i][j][r]);
      }

  // router: reduce over the 8 lanes sharing a row, then top-2
  #pragma unroll
  for (int e = 0; e < 8; ++e) {
    racc[e] += __shfl_xor(racc[e], 1, 64);
    racc[e] += __shfl_xor(racc[e], 2, 64);
    racc[e] += __shfl_xor(racc[e], 4, 64);
  }
  if ((t & 7) == 0) {
    int token = m0 + arow;
    f32x4 br0 = ((const f32x4*)br)[0], br1 = ((const f32x4*)br)[1];
    float l[8] = {racc[0] + br0.x, racc[1] + br0.y, racc[2] + br0.z, racc[3] + br0.w,
                  racc[4] + br1.x, racc[5] + br1.y, racc[6] + br1.z, racc[7] + br1.w};
    float best = -1e30f; int bi = 0;
    #pragma unroll
    for (int e = 0; e < 8; ++e) if (l[e] > best) { best = l[e]; bi = e; }
    float sec = -1e30f; int si = 0;
    #pragma unroll
    for (int e = 0; e < 8; ++e) if (e != bi && l[e] > sec) { sec = l[e]; si = e; }
    float w0 = 1.f / (1.f + expf(sec - best));
    topi[token * 2 + 0] = bi; topi[token * 2 + 1] = si;
    topw[token * 2 + 0] = w0; topw[token * 2 + 1] = 1.f - w0;
    atomicAdd(&lcnt[bi], 1);
    atomicAdd(&lcnt[si], 1);
  }
  __syncthreads();
  if (t < 8) atomicAdd(&ctrl[t], lcnt[t]);
}

// ---------------- bases: padded per-expert segments -------------------------
__global__ void k_bases(int* ctrl) {
  if (threadIdx.x == 0) {
    int cum = 0;
    for (int e = 0; e < 8; ++e) {
      int c = ctrl[e];
      int segs = (c + 127) >> 7;
      ctrl[8 + e] = cum;
      for (int s2 = 0; s2 < segs; ++s2) ctrl[16 + (cum >> 7) + s2] = e;
      cum += segs << 7;
    }
    for (int s2 = cum >> 7; s2 < NSEG_MAX; ++s2) ctrl[16 + s2] = -1;
  }
}

// ---------------- scatter tokens into per-expert pair lists + inverse map ---
__global__ __launch_bounds__(256) void k_scatter(const int* topi, const float* topw,
                                                 int* ctrl, int* pair_t, float* pair_w,
                                                 int* inv) {
  __shared__ int lcnt[8], lbase[8];
  int t = threadIdx.x;
  if (t < 8) lcnt[t] = 0;
  __syncthreads();
  int slot = blockIdx.x * 256 + t;
  int e = topi[slot];
  float wv = topw[slot];
  int lp = atomicAdd(&lcnt[e], 1);
  __syncthreads();
  if (t < 8) lbase[t] = atomicAdd(&ctrl[8 + t], lcnt[t]);
  __syncthreads();
  int p = lbase[e] + lp;
  pair_t[p] = slot >> 1;
  pair_w[p] = wv;
  inv[slot] = p;
}

// swizzled [128][64] tile reads (xo = (ln&7)<<3 must be defined)
#define GEMM_COMPUTE(AS, BS)                                                          \
  _Pragma("unroll")                                                                   \
  for (int ks = 0; ks < 2; ++ks) {                                                    \
    s16x8 af[4], bq[4];                                                               \
    _Pragma("unroll")                                                                 \
    for (int i = 0; i < 4; ++i)                                                       \
      af[i] = *(const s16x8*)&AS[(wr * 64 + i * 16 + ln) * 64 + ((ks * 32 + hi * 8) ^ xo)]; \
    _Pragma("unroll")                                                                 \
    for (int j = 0; j < 4; ++j)                                                       \
      bq[j] = *(const s16x8*)&BS[(wc * 64 + j * 16 + ln) * 64 + ((ks * 32 + hi * 8) ^ xo)]; \
    _Pragma("unroll")                                                                 \
    for (int i = 0; i < 4; ++i)                                                       \
      _Pragma("unroll")                                                               \
      for (int j = 0; j < 4; ++j)                                                     \
        acc[i][j] = __builtin_amdgcn_mfma_f32_16x16x32_bf16(af[i], bq[j], acc[i][j], 0, 0, 0); \
  }

#define SWZ8(idx) (((idx & 7) ^ ((idx >> 3) & 7)) * 8)

// ---------------- e1: hidden = gelu(gather(zb) @ W1[e] + b1) ---------------
__global__ __launch_bounds__(256, 2) void k_e1(const ushort_t* zb, const ushort_t* W1t,
                                               const float* b1, const int* ctrl,
                                               const int* pair_t, ushort_t* hidden) {
  __shared__ ushort_t As[2][8192];
  __shared__ ushort_t Bs[2][8192];
  __shared__ int pt[128];
  int sg = blockIdx.x >> 2, nt = blockIdx.x & 3;
  int e = ctrl[16 + sg];
  if (e < 0) return;
  int t = threadIdx.x;
  if (t < 128) pt[t] = pair_t[sg * 128 + t];
  __syncthreads();
  int n0 = nt * 128;
  const ushort_t* Bbase = W1t + (size_t)e * HH * RR;
  int lane = t & 63, wave = t >> 6;
  int wr = wave >> 1, wc = wave & 1;
  int ln = lane & 15, hi = lane >> 4;
  const int xo = (ln & 7) << 3;

  f32x4 acc[4][4];
  #pragma unroll
  for (int i = 0; i < 4; ++i)
    #pragma unroll
    for (int j = 0; j < 4; ++j) acc[i][j] = (f32x4){0.f, 0.f, 0.f, 0.f};

  #pragma unroll
  for (int u = 0; u < 4; ++u) {
    int idx = u * 256 + t;
    gll16(zb + (size_t)pt[idx >> 3] * RR + SWZ8(idx), &As[0][idx * 8]);
    gll16(Bbase + (size_t)(n0 + (idx >> 3)) * RR + SWZ8(idx), &Bs[0][idx * 8]);
  }
  __syncthreads();
  for (int s = 0; s < 4; ++s) {
    int cb = s & 1, xb = cb ^ 1;
    if (s < 3) {
      int k1 = (s + 1) * 64;
      #pragma unroll
      for (int u = 0; u < 4; ++u) {
        int idx = u * 256 + t;
        gll16(zb + (size_t)pt[idx >> 3] * RR + k1 + SWZ8(idx), &As[xb][idx * 8]);
        gll16(Bbase + (size_t)(n0 + (idx >> 3)) * RR + k1 + SWZ8(idx), &Bs[xb][idx * 8]);
      }
    }
    GEMM_COMPUTE(As[cb], Bs[cb]);
    __syncthreads();
  }
  #pragma unroll
  for (int i = 0; i < 4; ++i)
    #pragma unroll
    for (int j = 0; j < 4; ++j)
      #pragma unroll
      for (int r = 0; r < 4; ++r) {
        int pl = wr * 64 + i * 16 + hi * 4 + r;
        int col = n0 + wc * 64 + j * 16 + ln;
        float v = acc[i][j][r] + b1[e * HH + col];
        float g = 0.5f * v * (1.f + erff(v * 0.70710678118654752f));
        hidden[(size_t)(sg * 128 + pl) * HH + col] = f2bf(g);
      }
}

// ---------------- e2: eout[p] = w_p * (hidden @ W2[e] + b2)  (bf16 stores) --
__global__ __launch_bounds__(256, 2) void k_e2(const ushort_t* hidden, const ushort_t* W2t,
                                               const float* b2, const int* ctrl,
                                               const int* pair_t, const float* pair_w,
                                               ushort_t* eout) {
  __shared__ ushort_t As[2][8192];
  __shared__ ushort_t Bs[2][8192];
  __shared__ float pw[128];
  int sg = blockIdx.x >> 1, nt = blockIdx.x & 1;
  int e = ctrl[16 + sg];
  if (e < 0) return;
  int t = threadIdx.x;
  if (t < 128) pw[t] = pair_w[sg * 128 + t];
  __syncthreads();
  int n0 = nt * 128;
  const ushort_t* Abase = hidden + (size_t)sg * 128 * HH;
  const ushort_t* Bbase = W2t + (size_t)e * RR * HH;
  int lane = t & 63, wave = t >> 6;
  int wr = wave >> 1, wc = wave & 1;
  int ln = lane & 15, hi = lane >> 4;
  const int xo = (ln & 7) << 3;

  f32x4 acc[4][4];
  #pragma unroll
  for (int i = 0; i < 4; ++i)
    #pragma unroll
    for (int j = 0; j < 4; ++j) acc[i][j] = (f32x4){0.f, 0.f, 0.f, 0.f};

  #pragma unroll
  for (int u = 0; u < 4; ++u) {
    int idx = u * 256 + t;
    gll16(Abase + (size_t)(idx >> 3) * HH + SWZ8(idx), &As[0][idx * 8]);
    gll16(Bbase + (size_t)(n0 + (idx >> 3)) * HH + SWZ8(idx), &Bs[0][idx * 8]);
  }
  __syncthreads();
  for (int s = 0; s < 8; ++s) {
    int cb = s & 1, xb = cb ^ 1;
    if (s < 7) {
      int k1 = (s + 1) * 64;
      #pragma unroll
      for (int u = 0; u < 4; ++u) {
        int idx = u * 256 + t;
        gll16(Abase + (size_t)(idx >> 3) * HH + k1 + SWZ8(idx), &As[xb][idx * 8]);
        gll16(Bbase + (size_t)(n0 + (idx >> 3)) * HH + k1 + SWZ8(idx), &Bs[xb][idx * 8]);
      }
    }
    GEMM_COMPUTE(As[cb], Bs[cb]);
    __syncthreads();
  }
  #pragma unroll
  for (int i = 0; i < 4; ++i)
    #pragma unroll
    for (int j = 0; j < 4; ++j)
      #pragma unroll
      for (int r = 0; r < 4; ++r) {
        int pl = wr * 64 + i * 16 + hi * 4 + r;
        int col = n0 + wc * 64 + j * 16 + ln;
        float v = acc[i][j][r] + b2[e * RR + col];
        eout[(size_t)(sg * 128 + pl) * RR + col] = f2bf(pw[pl] * v);
      }
}

// ---------------- final: z_final = 0.75*z + 0.25*(eout0+eout1) -------------
__global__ __launch_bounds__(256) void k_final(const ushort_t* __restrict__ zb,
                                               const ushort_t* __restrict__ eout,
                                               const int* __restrict__ inv,
                                               const float* __restrict__ Uh,
                                               const float* __restrict__ bh,
                                               ushort_t* __restrict__ zb2,
                                               float* __restrict__ phalt) {
  __shared__ float luh[256];
  int t = threadIdx.x;
  if (t < 64) ((f32x4*)luh)[t] = ((const f32x4*)Uh)[t];
  __syncthreads();
  int tok = blockIdx.x * 64 + (t >> 2), q = t & 3;
  int i0 = inv[tok * 2], i1 = inv[tok * 2 + 1];
  const u16x8* z8 = (const u16x8*)(zb + (size_t)tok * RR + q * 64);
  const u16x8* ea = (const u16x8*)(eout + (size_t)i0 * RR + q * 64);
  const u16x8* eb = (const u16x8*)(eout + (size_t)i1 * RR + q * 64);
  ushort_t* o = zb2 + (size_t)tok * RR + q * 64;
  float acc = 0.f;
  #pragma unroll
  for (int it = 0; it < 8; ++it) {
    u16x8 zv = z8[it], av = ea[it], bv = eb[it];
    u16x8 pk;
    #pragma unroll
    for (int j = 0; j < 8; ++j) {
      float zf = 0.75f * bf2f(zv[j]) + 0.25f * (bf2f(av[j]) + bf2f(bv[j]));
      acc += zf * luh[q * 64 + it * 8 + j];
      pk[j] = f2bf(zf);
    }
    *(u16x8*)(o + it * 8) = pk;
  }
  acc += __shfl_xor(acc, 1, 64);
  acc += __shfl_xor(acc, 2, 64);
  if (q == 0) phalt[tok] = 1.f / (1.f + expf(-(acc + bh[0])));
}

// ---------------- gemm_u: h_new[T][D] = zb2 @ U ----------------------------
__global__ __launch_bounds__(256, 2) void k_gemm_u(const ushort_t* zb2, const ushort_t* Ut,
                                                   float* outp) {
  __shared__ ushort_t As[2][8192];
  __shared__ ushort_t Bs[2][8192];
  int hw = blockIdx.x;
  int bid = (hw & 7) * 256 + (hw >> 3);    // XCD swizzle (2048 = 8*256)
  int mt = bid >> 4, nt = bid & 15;
  int m0 = mt * 128, n0 = nt * 128;
  int t = threadIdx.x;
  int lane = t & 63, wave = t >> 6;
  int wr = wave >> 1, wc = wave & 1;
  int ln = lane & 15, hi = lane >> 4;
  const int xo = (ln & 7) << 3;

  f32x4 acc[4][4];
  #pragma unroll
  for (int i = 0; i < 4; ++i)
    #pragma unroll
    for (int j = 0; j < 4; ++j) acc[i][j] = (f32x4){0.f, 0.f, 0.f, 0.f};

  #pragma unroll
  for (int u = 0; u < 4; ++u) {
    int idx = u * 256 + t;
    gll16(zb2 + (size_t)(m0 + (idx >> 3)) * RR + SWZ8(idx), &As[0][idx * 8]);
    gll16(Ut + (size_t)(n0 + (idx >> 3)) * RR + SWZ8(idx), &Bs[0][idx * 8]);
  }
  __syncthreads();
  for (int s = 0; s < 4; ++s) {
    int cb = s & 1, xb = cb ^ 1;
    if (s < 3) {
      int k1 = (s + 1) * 64;
      #pragma unroll
      for (int u = 0; u < 4; ++u) {
        int idx = u * 256 + t;
        gll16(zb2 + (size_t)(m0 + (idx >> 3)) * RR + k1 + SWZ8(idx), &As[xb][idx * 8]);
        gll16(Ut + (size_t)(n0 + (idx >> 3)) * RR + k1 + SWZ8(idx), &Bs[xb][idx * 8]);
      }
    }
    GEMM_COMPUTE(As[cb], Bs[cb]);
    __syncthreads();
  }
  #pragma unroll
  for (int i = 0; i < 4; ++i)
    #pragma unroll
    for (int j = 0; j < 4; ++j)
      #pragma unroll
      for (int r = 0; r < 4; ++r) {
        int row = m0 + wr * 64 + i * 16 + hi * 4 + r;
        int col = n0 + wc * 64 + j * 16 + ln;
        outp[(size_t)row * DD + col] = acc[i][j][r];
      }
}

// ---------------------------------------------------------------------------
extern "C" void kernel_launch(void* const* d_in, const int* in_sizes, int n_in,
                              void* d_out, int out_size, void* d_ws, size_t ws_size,
                              hipStream_t stream) {
  (void)in_sizes; (void)n_in; (void)out_size;
  const float* h  = (const float*)d_in[0];
  const float* V  = (const float*)d_in[1];
  const float* U  = (const float*)d_in[2];
  const float* Wr = (const float*)d_in[3];
  const float* br = (const float*)d_in[4];
  const float* W1 = (const float*)d_in[5];
  const float* b1 = (const float*)d_in[6];
  const float* W2 = (const float*)d_in[7];
  const float* b2 = (const float*)d_in[8];
  const float* Wh = (const float*)d_in[9];
  const float* bh = (const float*)d_in[10];
  float* outp = (float*)d_out;
  char* w = (char*)d_ws;

  constexpr size_t OFF_VT    = 0;          // 1 MB   Vt   [256][2048] bf16
  constexpr size_t OFF_UT    = 1048576;    // 1 MB   Ut   [2048][256] bf16
  constexpr size_t OFF_W1T   = 2097152;    // 2 MB   W1t  [8][512][256] bf16
  constexpr size_t OFF_W2T   = 4194304;    // 2 MB   W2t  [8][256][512] bf16
  constexpr size_t OFF_VEFFT = 6291456;    // 64 KB  VeffT [8][2048] f32
  constexpr size_t OFF_UHV   = 6356992;    // 4 KB   Uh [256] f32
  constexpr size_t OFF_TOPI  = 6361088;    // 128 KB
  constexpr size_t OFF_TOPW  = 6492160;    // 128 KB
  constexpr size_t OFF_INV   = 6623232;    // 128 KB
  constexpr size_t OFF_CTRL  = 6754304;    // 4 KB
  constexpr size_t OFF_PT    = 6758400;    // 132 KB
  constexpr size_t OFF_PW    = 6893568;    // 132 KB
  constexpr size_t OFF_ZB    = 7028736;    // 8 MB   zb [16384][256] bf16
  constexpr size_t OFF_EOUT  = 15417344;   // 16.5MB eout [33792][256] bf16
  constexpr size_t OFF_HID   = 32718848;   // 33 MB  hidden [33792][512] bf16
  constexpr size_t OFF_ZB2   = OFF_HID;    // aliases hidden (dead after e2)
  constexpr size_t WS_NEED   = 67321856;
  if (ws_size < WS_NEED) return;

  ushort_t* Vt    = (ushort_t*)(w + OFF_VT);
  ushort_t* Ut    = (ushort_t*)(w + OFF_UT);
  ushort_t* W1t   = (ushort_t*)(w + OFF_W1T);
  ushort_t* W2t   = (ushort_t*)(w + OFF_W2T);
  float*    VeffT = (float*)(w + OFF_VEFFT);
  float*    Uh    = (float*)(w + OFF_UHV);
  int*      topi  = (int*)(w + OFF_TOPI);
  float*    topw  = (float*)(w + OFF_TOPW);
  int*      inv   = (int*)(w + OFF_INV);
  int*      ctrl  = (int*)(w + OFF_CTRL);
  int*      pair_t= (int*)(w + OFF_PT);
  float*    pair_w= (float*)(w + OFF_PW);
  ushort_t* zb    = (ushort_t*)(w + OFF_ZB);
  ushort_t* eout  = (ushort_t*)(w + OFF_EOUT);
  ushort_t* hidden= (ushort_t*)(w + OFF_HID);
  ushort_t* zb2   = (ushort_t*)(w + OFF_ZB2);

  // zero ctrl + pair lists (padding slots must have pt=0, pw=0)
  hipMemsetAsync(w + OFF_CTRL, 0, OFF_ZB - OFF_CTRL, stream);

  k_prep<<<3144, 256, 0, stream>>>(V, U, W1, W2, Wr, Wh, Vt, Ut, W1t, W2t, VeffT, Uh);
  k_front<<<512, 256, 0, stream>>>(h, Vt, VeffT, br, zb, topi, topw, ctrl);
  k_bases<<<1, 64, 0, stream>>>(ctrl);
  k_scatter<<<128, 256, 0, stream>>>(topi, topw, ctrl, pair_t, pair_w, inv);
  k_e1<<<NSEG_MAX * 4, 256, 0, stream>>>(zb, W1t, b1, ctrl, pair_t, hidden);
  k_e2<<<NSEG_MAX * 2, 256, 0, stream>>>(hidden, W2t, b2, ctrl, pair_t, pair_w, eout);
  k_final<<<256, 256, 0, stream>>>(zb, eout, inv, Uh, bh, zb2, outp + (size_t)TK * DD);
  k_gemm_u<<<2048, 256, 0, stream>>>(zb2, Ut, outp);
}

// Round 5
// 220.560 us; speedup vs baseline: 1.5480x; 1.0198x over previous
//
#include <hip/hip_runtime.h>
#include <stdint.h>
#include <math.h>

#define TK 16384
#define DD 2048
#define RR 256
#define EE 8
#define HH 512
#define NSEG_MAX 264
#define NPAIR_MAX (NSEG_MAX * 128)

typedef __attribute__((ext_vector_type(4))) float f32x4;
typedef __attribute__((ext_vector_type(8))) short s16x8;
typedef __attribute__((ext_vector_type(8))) unsigned short u16x8;
typedef __attribute__((ext_vector_type(4))) unsigned u32x4;
typedef unsigned short ushort_t;

__device__ inline unsigned short f2bf(float f) {
  union { float f; unsigned u; } v; v.f = f;
  unsigned r = v.u + 0x7fffu + ((v.u >> 16) & 1u);
  return (unsigned short)(r >> 16);
}
__device__ inline float bf2f(ushort_t u) {
  union { unsigned u; float f; } v; v.u = ((unsigned)u) << 16; return v.f;
}

__device__ inline void gll16(const void* g, void* l) {
  __builtin_amdgcn_global_load_lds(
      (const __attribute__((address_space(1))) void*)g,
      (__attribute__((address_space(3))) void*)l, 16, 0, 0);
}

__device__ inline u16x8 pack8(f32x4 a, f32x4 b) {
  u16x8 r;
  r[0] = f2bf(a.x); r[1] = f2bf(a.y); r[2] = f2bf(a.z); r[3] = f2bf(a.w);
  r[4] = f2bf(b.x); r[5] = f2bf(b.y); r[6] = f2bf(b.z); r[7] = f2bf(b.w);
  return r;
}

// LDS XOR-swizzle: LDS[row][slot] = G[row][slot ^ (row&7)] (8-elem bf16 slots)
#define SWZ8(idx) (((idx & 7) ^ ((idx >> 3) & 7)) * 8)

// ---------------- fused prep: 4 transposes + VeffT + Uh ---------------------
__global__ __launch_bounds__(256) void k_prep(
    const float* __restrict__ V, const float* __restrict__ U,
    const float* __restrict__ W1, const float* __restrict__ W2,
    const float* __restrict__ Wr, const float* __restrict__ Wh,
    ushort_t* __restrict__ Vt, ushort_t* __restrict__ Ut,
    ushort_t* __restrict__ W1t, ushort_t* __restrict__ W2t,
    float* __restrict__ VeffT, float* __restrict__ Uh) {
  __shared__ float sm[2112];
  int b = blockIdx.x, t = threadIdx.x;
  if (b < 3072) {
    const float* src; ushort_t* dst; int nr, nc, c0, r0;
    if (b < 512)       { src = V; dst = Vt; nr = 2048; nc = 256;
                         c0 = (b & 7) * 32; r0 = (b >> 3) * 32; }
    else if (b < 1024) { int bx = b - 512; src = U; dst = Ut; nr = 256; nc = 2048;
                         c0 = (bx & 63) * 32; r0 = (bx >> 6) * 32; }
    else if (b < 2048) { int bx = b - 1024; int s = bx >> 7; bx &= 127;
                         src = W1 + (size_t)s * 131072; dst = W1t + (size_t)s * 131072;
                         nr = 256; nc = 512; c0 = (bx & 15) * 32; r0 = (bx >> 4) * 32; }
    else               { int bx = b - 2048; int s = bx >> 7; bx &= 127;
                         src = W2 + (size_t)s * 131072; dst = W2t + (size_t)s * 131072;
                         nr = 512; nc = 256; c0 = (bx & 7) * 32; r0 = (bx >> 3) * 32; }
    int tx = t & 31, ty = t >> 5;
    #pragma unroll
    for (int i = 0; i < 32; i += 8)
      sm[(ty + i) * 33 + tx] = src[(size_t)(r0 + ty + i) * nc + c0 + tx];
    __syncthreads();
    #pragma unroll
    for (int i = 0; i < 32; i += 8)
      dst[(size_t)(c0 + ty + i) * nr + r0 + tx] = f2bf(sm[tx * 33 + ty + i]);
  } else if (b < 3080) {
    #pragma unroll
    for (int i = 0; i < 8; ++i) sm[i * 256 + t] = Wr[i * 256 + t];
    __syncthreads();
    int d = (b - 3072) * 256 + t;
    float a[8] = {0, 0, 0, 0, 0, 0, 0, 0};
    const float* vrow = V + (size_t)d * RR;
    for (int r = 0; r < RR; r += 4) {
      f32x4 v = *(const f32x4*)(vrow + r);
      #pragma unroll
      for (int e = 0; e < 8; ++e)
        a[e] += v.x * sm[r * 8 + e] + v.y * sm[(r + 1) * 8 + e] +
                v.z * sm[(r + 2) * 8 + e] + v.w * sm[(r + 3) * 8 + e];
    }
    #pragma unroll
    for (int e = 0; e < 8; ++e) VeffT[(size_t)e * DD + d] = a[e];
  } else {
    int wave = t >> 6, lane = t & 63;
    int r = (b - 3080) * 4 + wave;
    const f32x4* u4 = (const f32x4*)(U + (size_t)r * DD);
    const f32x4* w4 = (const f32x4*)Wh;
    float acc = 0.f;
    #pragma unroll
    for (int it = 0; it < 8; ++it) {
      f32x4 a = u4[it * 64 + lane], bb = w4[it * 64 + lane];
      acc += a.x * bb.x + a.y * bb.y + a.z * bb.z + a.w * bb.w;
    }
    #pragma unroll
    for (int o = 32; o; o >>= 1) acc += __shfl_down(acc, o, 64);
    if (lane == 0) Uh[r] = acc;
  }
}

// ---------------- fused front: z=h@V (bf16 MFMA) + exact-fp32 router --------
// tile 32 rows x 256 cols, K-step 64, 4 waves (each 32x64), grid 512.
// Bs XOR-swizzled (SWZ8 source + ^xo read) to kill the 16-way bank conflict.
__global__ __launch_bounds__(256, 2) void k_front(
    const float* __restrict__ h, const ushort_t* __restrict__ Vt,
    const float* __restrict__ VeffT, const float* __restrict__ br,
    ushort_t* __restrict__ zb, int* __restrict__ topi, float* __restrict__ topw,
    int* __restrict__ ctrl) {
  __shared__ ushort_t As[2][32 * 72];     // padded stride 72 (2-way, free)
  __shared__ ushort_t Bs[2][256 * 64];    // swizzled
  __shared__ float Vs[2][512];            // VeffT chunk [8][64]
  __shared__ int lcnt[8];
  int t = threadIdx.x;
  int m0 = blockIdx.x * 32;
  int lane = t & 63, wave = t >> 6;
  int ln = lane & 15, hi = lane >> 4;
  const int xo = (ln & 7) << 3;
  int arow = t >> 3, koff = (t & 7) * 8;
  const float* aptr = h + (size_t)(m0 + arow) * DD + koff;
  if (t < 8) lcnt[t] = 0;

  f32x4 acc[2][4];
  #pragma unroll
  for (int i = 0; i < 2; ++i)
    #pragma unroll
    for (int j = 0; j < 4; ++j) acc[i][j] = (f32x4){0.f, 0.f, 0.f, 0.f};
  float racc[8] = {0, 0, 0, 0, 0, 0, 0, 0};

  f32x4 pc0, pc1, pn0, pn1;
  {  // prologue k=0
    pc0 = ((const f32x4*)aptr)[0];
    pc1 = ((const f32x4*)aptr)[1];
    #pragma unroll
    for (int u = 0; u < 8; ++u) {
      int idx = u * 256 + t;
      gll16(Vt + (size_t)(idx >> 3) * DD + SWZ8(idx), &Bs[0][idx * 8]);
    }
    if (t < 128) gll16(VeffT + (size_t)(t >> 4) * DD + (t & 15) * 4, &Vs[0][t * 4]);
    *(u16x8*)&As[0][arow * 72 + koff] = pack8(pc0, pc1);
  }
  __syncthreads();

  for (int s = 0; s < 32; ++s) {
    int cb = s & 1, xb = cb ^ 1;
    int k1 = (s + 1) * 64;
    if (s < 31) {
      pn0 = ((const f32x4*)(aptr + k1))[0];
      pn1 = ((const f32x4*)(aptr + k1))[1];
      #pragma unroll
      for (int u = 0; u < 8; ++u) {
        int idx = u * 256 + t;
        gll16(Vt + (size_t)(idx >> 3) * DD + k1 + SWZ8(idx), &Bs[xb][idx * 8]);
      }
      if (t < 128) gll16(VeffT + (size_t)(t >> 4) * DD + k1 + (t & 15) * 4, &Vs[xb][t * 4]);
    }
    // exact-fp32 router partial on current chunk
    {
      const f32x4* vsb = (const f32x4*)&Vs[cb][0];
      #pragma unroll
      for (int e = 0; e < 8; ++e) {
        f32x4 v0 = vsb[(e * 64 + koff) >> 2];
        f32x4 v1 = vsb[((e * 64 + koff) >> 2) + 1];
        racc[e] += pc0.x * v0.x + pc0.y * v0.y + pc0.z * v0.z + pc0.w * v0.w +
                   pc1.x * v1.x + pc1.y * v1.y + pc1.z * v1.z + pc1.w * v1.w;
      }
    }
    #pragma unroll
    for (int ks = 0; ks < 2; ++ks) {
      s16x8 af[2], bq[4];
      #pragma unroll
      for (int i = 0; i < 2; ++i)
        af[i] = *(const s16x8*)&As[cb][(i * 16 + ln) * 72 + ks * 32 + hi * 8];
      #pragma unroll
      for (int j = 0; j < 4; ++j)
        bq[j] = *(const s16x8*)&Bs[cb][(wave * 64 + j * 16 + ln) * 64 + ((ks * 32 + hi * 8) ^ xo)];
      #pragma unroll
      for (int i = 0; i < 2; ++i)
        #pragma unroll
        for (int j = 0; j < 4; ++j)
          acc[i][j] = __builtin_amdgcn_mfma_f32_16x16x32_bf16(af[i], bq[j], acc[i][j], 0, 0, 0);
    }
    if (s < 31) {
      *(u16x8*)&As[xb][arow * 72 + koff] = pack8(pn0, pn1);
      pc0 = pn0; pc1 = pn1;
    }
    __syncthreads();
  }

  // z write
  #pragma unroll
  for (int i = 0; i < 2; ++i)
    #pragma unroll
    for (int j = 0; j < 4; ++j)
      #pragma unroll
      for (int r = 0; r < 4; ++r) {
        int row = m0 + i * 16 + hi * 4 + r;
        int col = wave * 64 + j * 16 + ln;
        zb[(size_t)row * RR + col] = f2bf(acc[i][j][r]);
      }

  // router: reduce over the 8 lanes sharing a row, then top-2
  #pragma unroll
  for (int e = 0; e < 8; ++e) {
    racc[e] += __shfl_xor(racc[e], 1, 64);
    racc[e] += __shfl_xor(racc[e], 2, 64);
    racc[e] += __shfl_xor(racc[e], 4, 64);
  }
  if ((t & 7) == 0) {
    int token = m0 + arow;
    f32x4 br0 = ((const f32x4*)br)[0], br1 = ((const f32x4*)br)[1];
    float l[8] = {racc[0] + br0.x, racc[1] + br0.y, racc[2] + br0.z, racc[3] + br0.w,
                  racc[4] + br1.x, racc[5] + br1.y, racc[6] + br1.z, racc[7] + br1.w};
    float best = -1e30f; int bi = 0;
    #pragma unroll
    for (int e = 0; e < 8; ++e) if (l[e] > best) { best = l[e]; bi = e; }
    float sec = -1e30f; int si = 0;
    #pragma unroll
    for (int e = 0; e < 8; ++e) if (e != bi && l[e] > sec) { sec = l[e]; si = e; }
    float w0 = 1.f / (1.f + expf(sec - best));
    topi[token * 2 + 0] = bi; topi[token * 2 + 1] = si;
    topw[token * 2 + 0] = w0; topw[token * 2 + 1] = 1.f - w0;
    atomicAdd(&lcnt[bi], 1);
    atomicAdd(&lcnt[si], 1);
  }
  __syncthreads();
  if (t < 8) atomicAdd(&ctrl[t], lcnt[t]);
}

// ---------------- bases: padded per-expert segments (parallel) --------------
// ctrl layout (ints): [0..7]=counts [8..15]=gcursor [16..16+264)=seg2expert
__global__ __launch_bounds__(256) void k_bases(int* ctrl) {
  __shared__ int sb[8], se[8];
  int t = threadIdx.x;
  if (t < 8) {
    int segs = (ctrl[t] + 127) >> 7;
    int scan = segs;
    #pragma unroll
    for (int o = 1; o < 8; o <<= 1) {
      int u2 = __shfl_up(scan, o, 64);
      if (t >= o) scan += u2;
    }
    int start = scan - segs;          // exclusive scan, segment units
    ctrl[8 + t] = start << 7;         // pair-slot cursor base
    sb[t] = start; se[t] = scan;
  }
  __syncthreads();
  for (int sg = t; sg < NSEG_MAX; sg += 256) {
    int e = -1;
    #pragma unroll
    for (int k = 0; k < 8; ++k)
      if (sg >= sb[k] && sg < se[k]) e = k;
    ctrl[16 + sg] = e;
  }
}

// ---------------- scatter tokens into per-expert pair lists + inverse map ---
__global__ __launch_bounds__(256) void k_scatter(const int* topi, const float* topw,
                                                 int* ctrl, int* pair_t, float* pair_w,
                                                 int* inv) {
  __shared__ int lcnt[8], lbase[8];
  int t = threadIdx.x;
  if (t < 8) lcnt[t] = 0;
  __syncthreads();
  int slot = blockIdx.x * 256 + t;
  int e = topi[slot];
  float wv = topw[slot];
  int lp = atomicAdd(&lcnt[e], 1);
  __syncthreads();
  if (t < 8) lbase[t] = atomicAdd(&ctrl[8 + t], lcnt[t]);
  __syncthreads();
  int p = lbase[e] + lp;
  pair_t[p] = slot >> 1;
  pair_w[p] = wv;
  inv[slot] = p;
}

// swizzled [128][64] tile reads (xo = (ln&7)<<3 must be defined)
#define GEMM_COMPUTE(AS, BS)                                                          \
  _Pragma("unroll")                                                                   \
  for (int ks = 0; ks < 2; ++ks) {                                                    \
    s16x8 af[4], bq[4];                                                               \
    _Pragma("unroll")                                                                 \
    for (int i = 0; i < 4; ++i)                                                       \
      af[i] = *(const s16x8*)&AS[(wr * 64 + i * 16 + ln) * 64 + ((ks * 32 + hi * 8) ^ xo)]; \
    _Pragma("unroll")                                                                 \
    for (int j = 0; j < 4; ++j)                                                       \
      bq[j] = *(const s16x8*)&BS[(wc * 64 + j * 16 + ln) * 64 + ((ks * 32 + hi * 8) ^ xo)]; \
    _Pragma("unroll")                                                                 \
    for (int i = 0; i < 4; ++i)                                                       \
      _Pragma("unroll")                                                               \
      for (int j = 0; j < 4; ++j)                                                     \
        acc[i][j] = __builtin_amdgcn_mfma_f32_16x16x32_bf16(af[i], bq[j], acc[i][j], 0, 0, 0); \
  }

// ---------------- e1: hidden = gelu(gather(zb) @ W1[e] + b1) ---------------
__global__ __launch_bounds__(256, 2) void k_e1(const ushort_t* zb, const ushort_t* W1t,
                                               const float* b1, const int* ctrl,
                                               const int* pair_t, ushort_t* hidden) {
  __shared__ ushort_t As[2][8192];
  __shared__ ushort_t Bs[2][8192];
  __shared__ int pt[128];
  int sg = blockIdx.x >> 2, nt = blockIdx.x & 3;
  int e = ctrl[16 + sg];
  if (e < 0) return;
  int t = threadIdx.x;
  if (t < 128) pt[t] = pair_t[sg * 128 + t];
  __syncthreads();
  int n0 = nt * 128;
  const ushort_t* Bbase = W1t + (size_t)e * HH * RR;
  int lane = t & 63, wave = t >> 6;
  int wr = wave >> 1, wc = wave & 1;
  int ln = lane & 15, hi = lane >> 4;
  const int xo = (ln & 7) << 3;

  f32x4 acc[4][4];
  #pragma unroll
  for (int i = 0; i < 4; ++i)
    #pragma unroll
    for (int j = 0; j < 4; ++j) acc[i][j] = (f32x4){0.f, 0.f, 0.f, 0.f};

  #pragma unroll
  for (int u = 0; u < 4; ++u) {
    int idx = u * 256 + t;
    gll16(zb + (size_t)pt[idx >> 3] * RR + SWZ8(idx), &As[0][idx * 8]);
    gll16(Bbase + (size_t)(n0 + (idx >> 3)) * RR + SWZ8(idx), &Bs[0][idx * 8]);
  }
  __syncthreads();
  for (int s = 0; s < 4; ++s) {
    int cb = s & 1, xb = cb ^ 1;
    if (s < 3) {
      int k1 = (s + 1) * 64;
      #pragma unroll
      for (int u = 0; u < 4; ++u) {
        int idx = u * 256 + t;
        gll16(zb + (size_t)pt[idx >> 3] * RR + k1 + SWZ8(idx), &As[xb][idx * 8]);
        gll16(Bbase + (size_t)(n0 + (idx >> 3)) * RR + k1 + SWZ8(idx), &Bs[xb][idx * 8]);
      }
    }
    GEMM_COMPUTE(As[cb], Bs[cb]);
    __syncthreads();
  }
  #pragma unroll
  for (int i = 0; i < 4; ++i)
    #pragma unroll
    for (int j = 0; j < 4; ++j)
      #pragma unroll
      for (int r = 0; r < 4; ++r) {
        int pl = wr * 64 + i * 16 + hi * 4 + r;
        int col = n0 + wc * 64 + j * 16 + ln;
        float v = acc[i][j][r] + b1[e * HH + col];
        float g = 0.5f * v * (1.f + erff(v * 0.70710678118654752f));
        hidden[(size_t)(sg * 128 + pl) * HH + col] = f2bf(g);
      }
}

// ---------------- e2: eout[p] = w_p * (hidden @ W2[e] + b2)  (bf16 stores) --
__global__ __launch_bounds__(256, 2) void k_e2(const ushort_t* hidden, const ushort_t* W2t,
                                               const float* b2, const int* ctrl,
                                               const int* pair_t, const float* pair_w,
                                               ushort_t* eout) {
  __shared__ ushort_t As[2][8192];
  __shared__ ushort_t Bs[2][8192];
  __shared__ float pw[128];
  int sg = blockIdx.x >> 1, nt = blockIdx.x & 1;
  int e = ctrl[16 + sg];
  if (e < 0) return;
  int t = threadIdx.x;
  if (t < 128) pw[t] = pair_w[sg * 128 + t];
  __syncthreads();
  int n0 = nt * 128;
  const ushort_t* Abase = hidden + (size_t)sg * 128 * HH;
  const ushort_t* Bbase = W2t + (size_t)e * RR * HH;
  int lane = t & 63, wave = t >> 6;
  int wr = wave >> 1, wc = wave & 1;
  int ln = lane & 15, hi = lane >> 4;
  const int xo = (ln & 7) << 3;

  f32x4 acc[4][4];
  #pragma unroll
  for (int i = 0; i < 4; ++i)
    #pragma unroll
    for (int j = 0; j < 4; ++j) acc[i][j] = (f32x4){0.f, 0.f, 0.f, 0.f};

  #pragma unroll
  for (int u = 0; u < 4; ++u) {
    int idx = u * 256 + t;
    gll16(Abase + (size_t)(idx >> 3) * HH + SWZ8(idx), &As[0][idx * 8]);
    gll16(Bbase + (size_t)(n0 + (idx >> 3)) * HH + SWZ8(idx), &Bs[0][idx * 8]);
  }
  __syncthreads();
  for (int s = 0; s < 8; ++s) {
    int cb = s & 1, xb = cb ^ 1;
    if (s < 7) {
      int k1 = (s + 1) * 64;
      #pragma unroll
      for (int u = 0; u < 4; ++u) {
        int idx = u * 256 + t;
        gll16(Abase + (size_t)(idx >> 3) * HH + k1 + SWZ8(idx), &As[xb][idx * 8]);
        gll16(Bbase + (size_t)(n0 + (idx >> 3)) * HH + k1 + SWZ8(idx), &Bs[xb][idx * 8]);
      }
    }
    GEMM_COMPUTE(As[cb], Bs[cb]);
    __syncthreads();
  }
  #pragma unroll
  for (int i = 0; i < 4; ++i)
    #pragma unroll
    for (int j = 0; j < 4; ++j)
      #pragma unroll
      for (int r = 0; r < 4; ++r) {
        int pl = wr * 64 + i * 16 + hi * 4 + r;
        int col = n0 + wc * 64 + j * 16 + ln;
        float v = acc[i][j][r] + b2[e * RR + col];
        eout[(size_t)(sg * 128 + pl) * RR + col] = f2bf(pw[pl] * v);
      }
}

// ---------------- final: z_final = 0.75*z + 0.25*(eout0+eout1) -------------
__global__ __launch_bounds__(256) void k_final(const ushort_t* __restrict__ zb,
                                               const ushort_t* __restrict__ eout,
                                               const int* __restrict__ inv,
                                               const float* __restrict__ Uh,
                                               const float* __restrict__ bh,
                                               ushort_t* __restrict__ zb2,
                                               float* __restrict__ phalt) {
  __shared__ float luh[256];
  int t = threadIdx.x;
  if (t < 64) ((f32x4*)luh)[t] = ((const f32x4*)Uh)[t];
  __syncthreads();
  int tok = blockIdx.x * 64 + (t >> 2), q = t & 3;
  int i0 = inv[tok * 2], i1 = inv[tok * 2 + 1];
  const u16x8* z8 = (const u16x8*)(zb + (size_t)tok * RR + q * 64);
  const u16x8* ea = (const u16x8*)(eout + (size_t)i0 * RR + q * 64);
  const u16x8* eb = (const u16x8*)(eout + (size_t)i1 * RR + q * 64);
  ushort_t* o = zb2 + (size_t)tok * RR + q * 64;
  float acc = 0.f;
  #pragma unroll
  for (int it = 0; it < 8; ++it) {
    u16x8 zv = z8[it], av = ea[it], bv = eb[it];
    u16x8 pk;
    #pragma unroll
    for (int j = 0; j < 8; ++j) {
      float zf = 0.75f * bf2f(zv[j]) + 0.25f * (bf2f(av[j]) + bf2f(bv[j]));
      acc += zf * luh[q * 64 + it * 8 + j];
      pk[j] = f2bf(zf);
    }
    *(u16x8*)(o + it * 8) = pk;
  }
  acc += __shfl_xor(acc, 1, 64);
  acc += __shfl_xor(acc, 2, 64);
  if (q == 0) phalt[tok] = 1.f / (1.f + expf(-(acc + bh[0])));
}

// ---------------- gemm_u: h_new[T][D] = zb2 @ U ----------------------------
__global__ __launch_bounds__(256, 2) void k_gemm_u(const ushort_t* zb2, const ushort_t* Ut,
                                                   float* outp) {
  __shared__ ushort_t As[2][8192];
  __shared__ ushort_t Bs[2][8192];
  int hw = blockIdx.x;
  int bid = (hw & 7) * 256 + (hw >> 3);    // XCD swizzle (2048 = 8*256)
  int mt = bid >> 4, nt = bid & 15;
  int m0 = mt * 128, n0 = nt * 128;
  int t = threadIdx.x;
  int lane = t & 63, wave = t >> 6;
  int wr = wave >> 1, wc = wave & 1;
  int ln = lane & 15, hi = lane >> 4;
  const int xo = (ln & 7) << 3;

  f32x4 acc[4][4];
  #pragma unroll
  for (int i = 0; i < 4; ++i)
    #pragma unroll
    for (int j = 0; j < 4; ++j) acc[i][j] = (f32x4){0.f, 0.f, 0.f, 0.f};

  #pragma unroll
  for (int u = 0; u < 4; ++u) {
    int idx = u * 256 + t;
    gll16(zb2 + (size_t)(m0 + (idx >> 3)) * RR + SWZ8(idx), &As[0][idx * 8]);
    gll16(Ut + (size_t)(n0 + (idx >> 3)) * RR + SWZ8(idx), &Bs[0][idx * 8]);
  }
  __syncthreads();
  for (int s = 0; s < 4; ++s) {
    int cb = s & 1, xb = cb ^ 1;
    if (s < 3) {
      int k1 = (s + 1) * 64;
      #pragma unroll
      for (int u = 0; u < 4; ++u) {
        int idx = u * 256 + t;
        gll16(zb2 + (size_t)(m0 + (idx >> 3)) * RR + k1 + SWZ8(idx), &As[xb][idx * 8]);
        gll16(Ut + (size_t)(n0 + (idx >> 3)) * RR + k1 + SWZ8(idx), &Bs[xb][idx * 8]);
      }
    }
    GEMM_COMPUTE(As[cb], Bs[cb]);
    __syncthreads();
  }
  #pragma unroll
  for (int i = 0; i < 4; ++i)
    #pragma unroll
    for (int j = 0; j < 4; ++j)
      #pragma unroll
      for (int r = 0; r < 4; ++r) {
        int row = m0 + wr * 64 + i * 16 + hi * 4 + r;
        int col = n0 + wc * 64 + j * 16 + ln;
        outp[(size_t)row * DD + col] = acc[i][j][r];
      }
}

// ---------------------------------------------------------------------------
extern "C" void kernel_launch(void* const* d_in, const int* in_sizes, int n_in,
                              void* d_out, int out_size, void* d_ws, size_t ws_size,
                              hipStream_t stream) {
  (void)in_sizes; (void)n_in; (void)out_size;
  const float* h  = (const float*)d_in[0];
  const float* V  = (const float*)d_in[1];
  const float* U  = (const float*)d_in[2];
  const float* Wr = (const float*)d_in[3];
  const float* br = (const float*)d_in[4];
  const float* W1 = (const float*)d_in[5];
  const float* b1 = (const float*)d_in[6];
  const float* W2 = (const float*)d_in[7];
  const float* b2 = (const float*)d_in[8];
  const float* Wh = (const float*)d_in[9];
  const float* bh = (const float*)d_in[10];
  float* outp = (float*)d_out;
  char* w = (char*)d_ws;

  constexpr size_t OFF_VT    = 0;          // 1 MB   Vt   [256][2048] bf16
  constexpr size_t OFF_UT    = 1048576;    // 1 MB   Ut   [2048][256] bf16
  constexpr size_t OFF_W1T   = 2097152;    // 2 MB   W1t  [8][512][256] bf16
  constexpr size_t OFF_W2T   = 4194304;    // 2 MB   W2t  [8][256][512] bf16
  constexpr size_t OFF_VEFFT = 6291456;    // 64 KB  VeffT [8][2048] f32
  constexpr size_t OFF_UHV   = 6356992;    // 4 KB   Uh [256] f32
  constexpr size_t OFF_TOPI  = 6361088;    // 128 KB
  constexpr size_t OFF_TOPW  = 6492160;    // 128 KB
  constexpr size_t OFF_INV   = 6623232;    // 128 KB
  constexpr size_t OFF_CTRL  = 6754304;    // 4 KB
  constexpr size_t OFF_PT    = 6758400;    // 132 KB
  constexpr size_t OFF_PW    = 6893568;    // 132 KB
  constexpr size_t OFF_ZB    = 7028736;    // 8 MB   zb [16384][256] bf16
  constexpr size_t OFF_EOUT  = 15417344;   // 16.5MB eout [33792][256] bf16
  constexpr size_t OFF_HID   = 32718848;   // 33 MB  hidden [33792][512] bf16
  constexpr size_t OFF_ZB2   = OFF_HID;    // aliases hidden (dead after e2)
  constexpr size_t WS_NEED   = 67321856;
  if (ws_size < WS_NEED) return;

  ushort_t* Vt    = (ushort_t*)(w + OFF_VT);
  ushort_t* Ut    = (ushort_t*)(w + OFF_UT);
  ushort_t* W1t   = (ushort_t*)(w + OFF_W1T);
  ushort_t* W2t   = (ushort_t*)(w + OFF_W2T);
  float*    VeffT = (float*)(w + OFF_VEFFT);
  float*    Uh    = (float*)(w + OFF_UHV);
  int*      topi  = (int*)(w + OFF_TOPI);
  float*    topw  = (float*)(w + OFF_TOPW);
  int*      inv   = (int*)(w + OFF_INV);
  int*      ctrl  = (int*)(w + OFF_CTRL);
  int*      pair_t= (int*)(w + OFF_PT);
  float*    pair_w= (float*)(w + OFF_PW);
  ushort_t* zb    = (ushort_t*)(w + OFF_ZB);
  ushort_t* eout  = (ushort_t*)(w + OFF_EOUT);
  ushort_t* hidden= (ushort_t*)(w + OFF_HID);
  ushort_t* zb2   = (ushort_t*)(w + OFF_ZB2);

  // zero ctrl + pair lists (padding slots must have pt=0, pw=0)
  hipMemsetAsync(w + OFF_CTRL, 0, OFF_ZB - OFF_CTRL, stream);

  k_prep<<<3144, 256, 0, stream>>>(V, U, W1, W2, Wr, Wh, Vt, Ut, W1t, W2t, VeffT, Uh);
  k_front<<<512, 256, 0, stream>>>(h, Vt, VeffT, br, zb, topi, topw, ctrl);
  k_bases<<<1, 256, 0, stream>>>(ctrl);
  k_scatter<<<128, 256, 0, stream>>>(topi, topw, ctrl, pair_t, pair_w, inv);
  k_e1<<<NSEG_MAX * 4, 256, 0, stream>>>(zb, W1t, b1, ctrl, pair_t, hidden);
  k_e2<<<NSEG_MAX * 2, 256, 0, stream>>>(hidden, W2t, b2, ctrl, pair_t, pair_w, eout);
  k_final<<<256, 256, 0, stream>>>(zb, eout, inv, Uh, bh, zb2, outp + (size_t)TK * DD);
  k_gemm_u<<<2048, 256, 0, stream>>>(zb2, Ut, outp);
}